// Round 8
// baseline (437.990 us; speedup 1.0000x reference)
//
#include <hip/hip_runtime.h>
#include <hip/hip_bf16.h>
#include <stdint.h>

using bf16 = __hip_bfloat16;
using u64 = unsigned long long;

constexpr int B_ = 2;
constexpr int N_ = 2304;   // 48*48 post-conv nodes

// Workspace layout (float offsets). Max = 1,339,456 floats = 5.36 MB.
constexpr int OFF_WC2   = 0;        // conv w  [tap][ic][oc] (9*64*64)
constexpr int OFF_WT2   = 36864;    // tconv w [tap][ic][oc]
constexpr int OFF_W1F   = 73728;    // [64][64]
constexpr int OFF_W2F   = 77824;
constexpr int OFF_WOUTF = 81920;    // [128][64]
constexpr int OFF_A1F   = 90112;    // 128
constexpr int OFF_A2F   = 90240;
constexpr int OFF_AOUTF = 90368;
constexpr int OFF_CBF   = 90496;    // 64
constexpr int OFF_TBF   = 90560;    // 64
constexpr int OFF_FLAG  = 90624;    // 1: fp32 inputs; 0: bf16
constexpr int OFF_SQ    = 90688;    // [B*N]; SQ + six s-arrays contiguous (zeroed by kc)
constexpr int OFF_S11   = 95296;
constexpr int OFF_S12   = 99904;
constexpr int OFF_S21   = 104512;
constexpr int OFF_S22   = 109120;
constexpr int OFF_S1O   = 113728;
constexpr int OFF_S2O   = 118336;
constexpr int OFF_KNN   = 122944;   // int [B*N][8] (7 used)
constexpr int OFF_BUF0  = 159808;   // 294912 floats each
constexpr int OFF_BUF1  = 454720;
constexpr int OFF_BUF2  = 749632;
constexpr int OFF_BUF3  = 1044544;
// Lifetimes:
//  BUF0: featT   (k1 -> k2 B-tiles, k_lin) -> h2       (attn12 -> lin2)
//  BUF1: Wh1_nc  (k_lin -> attn12)         -> Whout_nc (lin2 -> attn_out)
//  BUF2: feat_nc (k1 -> k2 A-rows)         -> h1       (attn12 -> lin2)
//  BUF3: Wh2_nc  (k_lin -> attn12)         -> g        (attn_out -> k7)

__device__ __forceinline__ float bf2f_raw(unsigned short u) {
    return __uint_as_float(((unsigned int)u) << 16);
}

// order-preserving float -> u32 map
__device__ __forceinline__ unsigned int mono32(float f) {
    unsigned int u = __float_as_uint(f);
    return (u & 0x80000000u) ? ~u : (u | 0x80000000u);
}

// Dtype probe: 64 low-halves of conv_w; fp32 misread -> huge bf16 values.
__device__ __forceinline__ bool detect_f32(const void* conv_w) {
    const unsigned short* cw = (const unsigned short*)conv_w;
    float m = 0.f;
    #pragma unroll
    for (int u = 0; u < 64; ++u) {
        float v = fabsf(bf2f_raw(cw[u]));
        if (v < 3.0e38f) m = fmaxf(m, v);
    }
    return m > 1.0e4f;
}

// ---------------------------------------------------------------------------
// KC: weight convert/transpose + zero s-arrays + write dtype flag.
// grid 144 x 256.
// ---------------------------------------------------------------------------
__global__ __launch_bounds__(256) void kc_prep(
    const void* conv_w, const void* conv_b, const void* W1, const void* a1,
    const void* W2, const void* a2, const void* Wout, const void* aout,
    const void* tconv_w, const void* tconv_b, float* __restrict__ ws)
{
    bool f32 = detect_f32(conv_w);
    int idx = blockIdx.x * 256 + threadIdx.x;   // < 36864
    if (idx == 0) ws[OFF_FLAG] = f32 ? 1.f : 0.f;
    if (idx < 32256) ws[OFF_SQ + idx] = 0.f;    // SQ..S2O zero-init

    {
        int tap = idx >> 12, ic = (idx >> 6) & 63, oc = idx & 63;
        if (f32) {
            ws[OFF_WC2 + idx] = ((const float*)conv_w)[(oc * 64 + ic) * 9 + tap];
            ws[OFF_WT2 + idx] = ((const float*)tconv_w)[(ic * 64 + oc) * 9 + tap];
        } else {
            ws[OFF_WC2 + idx] = bf2f_raw(((const unsigned short*)conv_w)[(oc * 64 + ic) * 9 + tap]);
            ws[OFF_WT2 + idx] = bf2f_raw(((const unsigned short*)tconv_w)[(ic * 64 + oc) * 9 + tap]);
        }
    }
    if (idx < 4096) {
        if (f32) {
            ws[OFF_W1F + idx] = ((const float*)W1)[idx];
            ws[OFF_W2F + idx] = ((const float*)W2)[idx];
        } else {
            ws[OFF_W1F + idx] = bf2f_raw(((const unsigned short*)W1)[idx]);
            ws[OFF_W2F + idx] = bf2f_raw(((const unsigned short*)W2)[idx]);
        }
    }
    if (idx < 8192)
        ws[OFF_WOUTF + idx] = f32 ? ((const float*)Wout)[idx]
                                  : bf2f_raw(((const unsigned short*)Wout)[idx]);
    if (idx < 128) {
        if (f32) {
            ws[OFF_A1F + idx]   = ((const float*)a1)[idx];
            ws[OFF_A2F + idx]   = ((const float*)a2)[idx];
            ws[OFF_AOUTF + idx] = ((const float*)aout)[idx];
        } else {
            ws[OFF_A1F + idx]   = bf2f_raw(((const unsigned short*)a1)[idx]);
            ws[OFF_A2F + idx]   = bf2f_raw(((const unsigned short*)a2)[idx]);
            ws[OFF_AOUTF + idx] = bf2f_raw(((const unsigned short*)aout)[idx]);
        }
    }
    if (idx < 64) {
        if (f32) {
            ws[OFF_CBF + idx] = ((const float*)conv_b)[idx];
            ws[OFF_TBF + idx] = ((const float*)tconv_b)[idx];
        } else {
            ws[OFF_CBF + idx] = bf2f_raw(((const unsigned short*)conv_b)[idx]);
            ws[OFF_TBF + idx] = bf2f_raw(((const unsigned short*)tconv_b)[idx]);
        }
    }
}

// ---------------------------------------------------------------------------
// K1: 3x3 stride-2 conv pad 1 + fused sq atomic.  Reads x directly (dual
// dtype).  Writes featT (BUF0, channel-major) and feat_nc (BUF2, node-major).
// grid (18, 8 oc, B) x 128.
// ---------------------------------------------------------------------------
template <bool F32>
__device__ __forceinline__ void conv_body(const void* __restrict__ x,
                                          float* __restrict__ ws,
                                          int n, int ocb, int b)
{
    int oy = n / 48, ox = n - (n / 48) * 48;
    const float* wc2 = ws + OFF_WC2;
    size_t xb = (size_t)b * 64 * 9216;
    float acc[8] = {0, 0, 0, 0, 0, 0, 0, 0};

    for (int ky = 0; ky < 3; ++ky) {
        int iy = 2 * oy - 1 + ky;
        bool vy = (unsigned)iy < 96u;
        int iyc = vy ? iy : 0;
        for (int kx = 0; kx < 3; ++kx) {
            int ix = 2 * ox - 1 + kx;
            bool v = vy && ((unsigned)ix < 96u);
            int ixc = v ? ix : 0;
            size_t xoff = xb + iyc * 96 + ixc;
            const float* wb = wc2 + (ky * 3 + kx) * 4096 + ocb;
            #pragma unroll 8
            for (int ic = 0; ic < 64; ++ic) {
                float xv;
                if (F32) xv = ((const float*)x)[xoff + ic * 9216];
                else     xv = bf2f_raw(((const unsigned short*)x)[xoff + ic * 9216]);
                xv = v ? xv : 0.f;
                const float* wr = wb + ic * 64;
                #pragma unroll
                for (int o = 0; o < 8; ++o) acc[o] += xv * wr[o];
            }
        }
    }
    float* featT = ws + OFF_BUF0 + (size_t)b * 64 * N_;
    const float* cb = ws + OFF_CBF;
    float ssum = 0.f;
    #pragma unroll
    for (int o = 0; o < 8; ++o) {
        float f = acc[o] + cb[ocb + o];
        acc[o] = f;
        featT[(ocb + o) * N_ + n] = f;
        ssum += f * f;
    }
    float4* fnc = (float4*)(ws + OFF_BUF2 + ((size_t)(b * N_ + n) * 64 + ocb));
    fnc[0] = make_float4(acc[0], acc[1], acc[2], acc[3]);
    fnc[1] = make_float4(acc[4], acc[5], acc[6], acc[7]);
    atomicAdd(ws + OFF_SQ + b * N_ + n, ssum);
}

__global__ __launch_bounds__(128) void k1_conv(const void* __restrict__ x,
                                               float* __restrict__ ws)
{
    int n   = blockIdx.x * 128 + threadIdx.x;   // 0..2303
    int ocb = blockIdx.y * 8;
    int b   = blockIdx.z;
    if (ws[OFF_FLAG] != 0.f) conv_body<true >(x, ws, n, ocb, b);
    else                     conv_body<false>(x, ws, n, ocb, b);
}

// ---------------------------------------------------------------------------
// K2: exact top-7 per row, LDS-tiled GEMM + fused ballot selection.
// Block = 256 thr = 4 waves = 16 rows, covering ALL j (36 tiles of 64).
// A (16 rows x 64c) staged once from node-major feat_nc; per tile B (64k x 64j)
// staged COALESCED from channel-major featT.  Wave owns 4 rows; per k4-chunk:
// 4 B-b32 (lane-consecutive, conflict-free) + 4 A-b128 (wave-uniform
// broadcast) + 16 FMA.  Rank key u64 (mono(y)<<32|j): strict < == stable
// argsort order.  Per tile, per row: ballot(key < K[6]) -> rare survivors
// inserted serially (wave-uniform control, static indexing only).
// grid 288 x 256.
// ---------------------------------------------------------------------------
__global__ __launch_bounds__(256) void k2_knn(float* __restrict__ ws)
{
    __shared__ float As[16][64];
    __shared__ float Bs[64][64];
    int tid = threadIdx.x;
    int i0  = blockIdx.x * 16;            // global row base (16 | N_)
    int b   = i0 / N_;
    const float* fT = ws + OFF_BUF0 + (size_t)b * 64 * N_;
    const float* sq = ws + OFF_SQ + b * N_;
    int w = tid >> 6, lane = tid & 63;
    int r0 = w * 4;

    {   // stage A rows (node-major, coalesced float4)
        int r = tid >> 4, c4 = tid & 15;
        float4 v = ((const float4*)(ws + OFF_BUF2))[(size_t)(i0 + r) * 16 + c4];
        As[r][c4 * 4 + 0] = v.x; As[r][c4 * 4 + 1] = v.y;
        As[r][c4 * 4 + 2] = v.z; As[r][c4 * 4 + 3] = v.w;
    }

    u64 K[4][7];
    #pragma unroll
    for (int r = 0; r < 4; ++r)
        #pragma unroll
        for (int t = 0; t < 7; ++t) K[r][t] = ~0ull;

    __syncthreads();

    for (int jt = 0; jt < 36; ++jt) {
        int j0 = jt * 64;
        // stage B tile: Bs[k][j], coalesced global reads
        #pragma unroll 4
        for (int it = 0; it < 16; ++it) {
            int k = w + it * 4;
            Bs[k][lane] = fT[(size_t)k * N_ + j0 + lane];
        }
        __syncthreads();

        float sqj = sq[j0 + lane];
        float4 acc[4];
        #pragma unroll
        for (int r = 0; r < 4; ++r) acc[r] = make_float4(0.f, 0.f, 0.f, 0.f);
        #pragma unroll 2
        for (int k4 = 0; k4 < 16; ++k4) {
            float b0 = Bs[k4 * 4 + 0][lane];
            float b1 = Bs[k4 * 4 + 1][lane];
            float b2 = Bs[k4 * 4 + 2][lane];
            float b3 = Bs[k4 * 4 + 3][lane];
            #pragma unroll
            for (int r = 0; r < 4; ++r) {
                float4 av = *(const float4*)&As[r0 + r][k4 * 4];
                acc[r].x += av.x * b0; acc[r].y += av.y * b1;
                acc[r].z += av.z * b2; acc[r].w += av.w * b3;
            }
        }

        #pragma unroll
        for (int r = 0; r < 4; ++r) {
            float y = sqj - 2.f * ((acc[r].x + acc[r].y) + (acc[r].z + acc[r].w));
            u64 key = ((u64)mono32(y) << 32) | (unsigned int)(j0 + lane);
            u64 mask = __ballot(key < K[r][6]);
            while (mask) {
                int l = (int)__builtin_ctzll(mask);
                mask &= mask - 1;
                u64 kl = ((u64)(unsigned int)__shfl((int)(key >> 32), l) << 32)
                       | (unsigned int)__shfl((int)(key & 0xffffffffu), l);
                if (kl < K[r][6]) {
                    int pos = 0;
                    #pragma unroll
                    for (int s = 0; s < 7; ++s) pos += (K[r][s] < kl) ? 1 : 0;
                    #pragma unroll
                    for (int p = 6; p > 0; --p)
                        K[r][p] = (p == pos) ? kl : ((p > pos) ? K[r][p - 1] : K[r][p]);
                    if (pos == 0) K[r][0] = kl;
                }
            }
        }
        __syncthreads();
    }

    // K lists are wave-uniform & sorted ascending; lanes 0..6 write KNN.
    int* knn = (int*)(ws + OFF_KNN);
    if (lane < 7) {
        #pragma unroll
        for (int r = 0; r < 4; ++r)
            knn[(size_t)(i0 + r0 + r) * 8 + lane] = (int)(K[r][lane] & 0xffffffffull);
    }
}

// ---------------------------------------------------------------------------
// K_lin: both GAT input projections; node-major Wh_nc out + s1/s2 atomics.
// grid (18, 8 oc, 2 layers) x 256.
// ---------------------------------------------------------------------------
__global__ __launch_bounds__(256) void k_lin(float* __restrict__ ws)
{
    int layer = blockIdx.z;
    const float* W  = ws + (layer ? OFF_W2F : OFF_W1F);
    const float* a  = ws + (layer ? OFF_A2F : OFF_A1F);
    float* out_nc   = ws + (layer ? OFF_BUF3 : OFF_BUF1);
    float* s1       = ws + (layer ? OFF_S21 : OFF_S11);
    float* s2       = ws + (layer ? OFF_S22 : OFF_S12);
    int ocb = blockIdx.y * 8;
    int i = blockIdx.x * 256 + threadIdx.x;
    int b = i / N_, n = i - b * N_;
    const float* in_b = ws + OFF_BUF0 + (size_t)b * 64 * N_;

    float acc[8] = {0, 0, 0, 0, 0, 0, 0, 0};
    #pragma unroll 8
    for (int kk = 0; kk < 64; ++kk) {
        float xv = in_b[kk * N_ + n];
        const float* wr = W + kk * 64 + ocb;
        #pragma unroll
        for (int o = 0; o < 8; ++o) acc[o] += xv * wr[o];
    }
    float4* ob = (float4*)(out_nc + ((size_t)i * 64 + ocb));
    ob[0] = make_float4(acc[0], acc[1], acc[2], acc[3]);
    ob[1] = make_float4(acc[4], acc[5], acc[6], acc[7]);
    float p1 = 0.f, p2 = 0.f;
    #pragma unroll
    for (int o = 0; o < 8; ++o) {
        p1 += acc[o] * a[ocb + o];
        p2 += acc[o] * a[64 + ocb + o];
    }
    atomicAdd(s1 + i, p1);
    atomicAdd(s2 + i, p2);
}

// ---------------------------------------------------------------------------
// K_lin2: Whout_nc = [h1|h2] @ Wout.  h1=BUF2, h2=BUF0 (channel-major),
// out=BUF1 node-major.  grid (18, 8) x 256.
// ---------------------------------------------------------------------------
__global__ __launch_bounds__(256) void k_lin2(float* __restrict__ ws)
{
    int ocb = blockIdx.y * 8;
    int i = blockIdx.x * 256 + threadIdx.x;
    int b = i / N_, n = i - b * N_;
    const float* h1 = ws + OFF_BUF2 + (size_t)b * 64 * N_;
    const float* h2 = ws + OFF_BUF0 + (size_t)b * 64 * N_;
    const float* W  = ws + OFF_WOUTF;
    const float* a  = ws + OFF_AOUTF;

    float acc[8] = {0, 0, 0, 0, 0, 0, 0, 0};
    #pragma unroll 8
    for (int kk = 0; kk < 64; ++kk) {
        float xv = h1[kk * N_ + n];
        const float* wr = W + kk * 64 + ocb;
        #pragma unroll
        for (int o = 0; o < 8; ++o) acc[o] += xv * wr[o];
    }
    #pragma unroll 8
    for (int kk = 0; kk < 64; ++kk) {
        float xv = h2[kk * N_ + n];
        const float* wr = W + (64 + kk) * 64 + ocb;
        #pragma unroll
        for (int o = 0; o < 8; ++o) acc[o] += xv * wr[o];
    }
    float4* ob = (float4*)(ws + OFF_BUF1 + ((size_t)i * 64 + ocb));
    ob[0] = make_float4(acc[0], acc[1], acc[2], acc[3]);
    ob[1] = make_float4(acc[4], acc[5], acc[6], acc[7]);
    float p1 = 0.f, p2 = 0.f;
    #pragma unroll
    for (int o = 0; o < 8; ++o) {
        p1 += acc[o] * a[ocb + o];
        p2 += acc[o] * a[64 + ocb + o];
    }
    atomicAdd(ws + OFF_S1O + i, p1);
    atomicAdd(ws + OFF_S2O + i, p2);
}

// ---------------------------------------------------------------------------
// attention body: softmax over 7-NN + ELU, one float4 channel group.
// ---------------------------------------------------------------------------
__device__ __forceinline__ void attn_body(
    const float* __restrict__ Wh_nc, const float* __restrict__ s1,
    const float* __restrict__ s2, const int* __restrict__ knn,
    float* __restrict__ out, int i, int b, int n, int c4)
{
    const int* kp = knn + (size_t)i * 8;
    int j[7];
    #pragma unroll
    for (int t = 0; t < 7; ++t) {
        int jt = kp[t];
        j[t] = ((unsigned)jt < (unsigned)N_) ? jt : 0;
    }
    float si = s1[i];
    const float* s2b = s2 + b * N_;
    float e[7];
    #pragma unroll
    for (int t = 0; t < 7; ++t) {
        float v = si + s2b[j[t]];
        e[t] = v > 0.f ? v : 0.2f * v;     // leaky_relu 0.2
    }
    float m = e[0];
    #pragma unroll
    for (int t = 1; t < 7; ++t) m = fmaxf(m, e[t]);
    float ssum = 0.f;
    #pragma unroll
    for (int t = 0; t < 7; ++t) { e[t] = __expf(e[t] - m); ssum += e[t]; }
    float inv = 1.f / ssum;
    #pragma unroll
    for (int t = 0; t < 7; ++t) e[t] *= inv;

    const float4* W4 = (const float4*)Wh_nc;
    float4 acc = make_float4(0.f, 0.f, 0.f, 0.f);
    #pragma unroll
    for (int t = 0; t < 7; ++t) {
        float4 v = W4[(size_t)(b * N_ + j[t]) * 16 + c4];
        acc.x += e[t] * v.x; acc.y += e[t] * v.y;
        acc.z += e[t] * v.z; acc.w += e[t] * v.w;
    }
    acc.x = acc.x > 0.f ? acc.x : expm1f(acc.x);
    acc.y = acc.y > 0.f ? acc.y : expm1f(acc.y);
    acc.z = acc.z > 0.f ? acc.z : expm1f(acc.z);
    acc.w = acc.w > 0.f ? acc.w : expm1f(acc.w);
    float* ob = out + (size_t)b * 64 * N_;
    ob[(c4 * 4 + 0) * N_ + n] = acc.x;
    ob[(c4 * 4 + 1) * N_ + n] = acc.y;
    ob[(c4 * 4 + 2) * N_ + n] = acc.z;
    ob[(c4 * 4 + 3) * N_ + n] = acc.w;
}

// grid (18, 16 c4-groups, 2 layers) x 256
__global__ __launch_bounds__(256) void k_attn12(float* __restrict__ ws)
{
    int layer = blockIdx.z;
    const float* Wh_nc = ws + (layer ? OFF_BUF3 : OFF_BUF1);
    const float* s1    = ws + (layer ? OFF_S21 : OFF_S11);
    const float* s2    = ws + (layer ? OFF_S22 : OFF_S12);
    float* out         = ws + (layer ? OFF_BUF0 : OFF_BUF2);
    int c4 = blockIdx.y;
    int i = blockIdx.x * 256 + threadIdx.x;
    int b = i / N_, n = i - b * N_;
    attn_body(Wh_nc, s1, s2, (const int*)(ws + OFF_KNN), out, i, b, n, c4);
}

// grid (18, 16) x 256
__global__ __launch_bounds__(256) void k_attn_out(float* __restrict__ ws)
{
    int c4 = blockIdx.y;
    int i = blockIdx.x * 256 + threadIdx.x;
    int b = i / N_, n = i - b * N_;
    attn_body(ws + OFF_BUF1, ws + OFF_S1O, ws + OFF_S2O,
              (const int*)(ws + OFF_KNN), ws + OFF_BUF3, i, b, n, c4);
}

// ---------------------------------------------------------------------------
// K7: ConvTranspose2d k=3 s=2 p=1 op=1 : 48x48 -> 96x96, reads g=BUF3.
// grid (36, 8 oc, B) x 256; dual-dtype output store via ws flag.
// ---------------------------------------------------------------------------
__global__ __launch_bounds__(256) void k7_tconv(float* __restrict__ ws,
                                                void* __restrict__ outp)
{
    bool f32 = ws[OFF_FLAG] != 0.f;
    int pix = blockIdx.x * 256 + threadIdx.x;   // 0..9215
    int ocb = blockIdx.y * 8;
    int b   = blockIdx.z;
    int oy = pix / 96, ox = pix - (pix / 96) * 96;

    const float* gT  = ws + OFF_BUF3 + (size_t)b * 64 * N_;
    const float* wt2 = ws + OFF_WT2;
    float acc[8] = {0, 0, 0, 0, 0, 0, 0, 0};

    for (int ky = 0; ky < 3; ++ky) {
        int ty = oy + 1 - ky;
        bool vy = ((ty & 1) == 0) && ((unsigned)(ty >> 1) < 48u);
        int iy = vy ? (ty >> 1) : 0;
        for (int kx = 0; kx < 3; ++kx) {
            int tx = ox + 1 - kx;
            bool v = vy && ((tx & 1) == 0) && ((unsigned)(tx >> 1) < 48u);
            int ix = v ? (tx >> 1) : 0;
            const float* gp = gT + iy * 48 + ix;
            const float* wb = wt2 + (ky * 3 + kx) * 4096 + ocb;
            #pragma unroll 8
            for (int ic = 0; ic < 64; ++ic) {
                float gv = gp[ic * N_];
                gv = v ? gv : 0.f;
                const float* wr = wb + ic * 64;
                #pragma unroll
                for (int o = 0; o < 8; ++o) acc[o] += gv * wr[o];
            }
        }
    }
    const float* tb = ws + OFF_TBF;
    size_t base = ((size_t)(b * 64 + ocb) * 96 + oy) * 96 + ox;
    if (f32) {
        float* op = (float*)outp;
        #pragma unroll
        for (int o = 0; o < 8; ++o) op[base + (size_t)o * 9216] = acc[o] + tb[ocb + o];
    } else {
        bf16* op = (bf16*)outp;
        #pragma unroll
        for (int o = 0; o < 8; ++o)
            op[base + (size_t)o * 9216] = __float2bfloat16(acc[o] + tb[ocb + o]);
    }
}

// ---------------------------------------------------------------------------
extern "C" void kernel_launch(void* const* d_in, const int* in_sizes, int n_in,
                              void* d_out, int out_size, void* d_ws, size_t ws_size,
                              hipStream_t stream)
{
    float* ws = (float*)d_ws;

    hipLaunchKernelGGL(kc_prep, dim3(144), dim3(256), 0, stream,
                       d_in[1], d_in[2], d_in[3], d_in[4], d_in[5], d_in[6],
                       d_in[7], d_in[8], d_in[9], d_in[10], ws);
    hipLaunchKernelGGL(k1_conv, dim3(18, 8, 2), dim3(128), 0, stream, d_in[0], ws);
    hipLaunchKernelGGL(k2_knn, dim3(288), dim3(256), 0, stream, ws);
    hipLaunchKernelGGL(k_lin, dim3(18, 8, 2), dim3(256), 0, stream, ws);
    hipLaunchKernelGGL(k_attn12, dim3(18, 16, 2), dim3(256), 0, stream, ws);
    hipLaunchKernelGGL(k_lin2, dim3(18, 8), dim3(256), 0, stream, ws);
    hipLaunchKernelGGL(k_attn_out, dim3(18, 16), dim3(256), 0, stream, ws);
    hipLaunchKernelGGL(k7_tconv, dim3(36, 8, 2), dim3(256), 0, stream, ws, d_out);
}

// Round 9
// 301.635 us; speedup vs baseline: 1.4521x; 1.4521x over previous
//
#include <hip/hip_runtime.h>
#include <hip/hip_bf16.h>
#include <stdint.h>

using bf16 = __hip_bfloat16;
using u64 = unsigned long long;

constexpr int B_ = 2;
constexpr int N_ = 2304;   // 48*48 post-conv nodes

// Workspace layout (float offsets). Max = 1,339,456 floats = 5.36 MB.
constexpr int OFF_WC2   = 0;        // conv w  [tap][ic][oc] (9*64*64)
constexpr int OFF_WT2   = 36864;    // tconv w [tap][ic][oc]
constexpr int OFF_W1F   = 73728;    // [64][64]
constexpr int OFF_W2F   = 77824;
constexpr int OFF_WOUTF = 81920;    // [128][64]
constexpr int OFF_A1F   = 90112;    // 128
constexpr int OFF_A2F   = 90240;
constexpr int OFF_AOUTF = 90368;
constexpr int OFF_CBF   = 90496;    // 64
constexpr int OFF_TBF   = 90560;    // 64
constexpr int OFF_FLAG  = 90624;    // 1: fp32 inputs; 0: bf16
constexpr int OFF_SQ    = 90688;    // [B*N]; SQ + six s-arrays contiguous (zeroed by kc)
constexpr int OFF_S11   = 95296;
constexpr int OFF_S12   = 99904;
constexpr int OFF_S21   = 104512;
constexpr int OFF_S22   = 109120;
constexpr int OFF_S1O   = 113728;
constexpr int OFF_S2O   = 118336;
constexpr int OFF_KNN   = 122944;   // int [B*N][8] (7 used)
constexpr int OFF_BUF0  = 159808;   // 294912 floats each
constexpr int OFF_BUF1  = 454720;
constexpr int OFF_BUF2  = 749632;
constexpr int OFF_BUF3  = 1044544;
// Lifetimes:
//  BUF0: featT   (k1 -> k2 B-tiles, k_lin) -> h2       (attn12 -> lin2)
//  BUF1: Wh1_nc  (k_lin -> attn12)         -> Whout_nc (lin2 -> attn_out)
//  BUF2: feat_nc (k1 -> k2 A-rows)         -> h1       (attn12 -> lin2)
//  BUF3: PK u64[4608][3][8] (k2->k2_merge) -> Wh2_nc (k_lin->attn12) -> g (attn_out->k7)
constexpr int OFF_PK    = OFF_BUF3;

__device__ __forceinline__ float bf2f_raw(unsigned short u) {
    return __uint_as_float(((unsigned int)u) << 16);
}

// order-preserving float -> u32 map
__device__ __forceinline__ unsigned int mono32(float f) {
    unsigned int u = __float_as_uint(f);
    return (u & 0x80000000u) ? ~u : (u | 0x80000000u);
}

// Dtype probe: 64 low-halves of conv_w; fp32 misread -> huge bf16 values.
__device__ __forceinline__ bool detect_f32(const void* conv_w) {
    const unsigned short* cw = (const unsigned short*)conv_w;
    float m = 0.f;
    #pragma unroll
    for (int u = 0; u < 64; ++u) {
        float v = fabsf(bf2f_raw(cw[u]));
        if (v < 3.0e38f) m = fmaxf(m, v);
    }
    return m > 1.0e4f;
}

// ---------------------------------------------------------------------------
// KC: weight convert/transpose + zero s-arrays + write dtype flag.
// grid 144 x 256.
// ---------------------------------------------------------------------------
__global__ __launch_bounds__(256) void kc_prep(
    const void* conv_w, const void* conv_b, const void* W1, const void* a1,
    const void* W2, const void* a2, const void* Wout, const void* aout,
    const void* tconv_w, const void* tconv_b, float* __restrict__ ws)
{
    bool f32 = detect_f32(conv_w);
    int idx = blockIdx.x * 256 + threadIdx.x;   // < 36864
    if (idx == 0) ws[OFF_FLAG] = f32 ? 1.f : 0.f;
    if (idx < 32256) ws[OFF_SQ + idx] = 0.f;    // SQ..S2O zero-init

    {
        int tap = idx >> 12, ic = (idx >> 6) & 63, oc = idx & 63;
        if (f32) {
            ws[OFF_WC2 + idx] = ((const float*)conv_w)[(oc * 64 + ic) * 9 + tap];
            ws[OFF_WT2 + idx] = ((const float*)tconv_w)[(ic * 64 + oc) * 9 + tap];
        } else {
            ws[OFF_WC2 + idx] = bf2f_raw(((const unsigned short*)conv_w)[(oc * 64 + ic) * 9 + tap]);
            ws[OFF_WT2 + idx] = bf2f_raw(((const unsigned short*)tconv_w)[(ic * 64 + oc) * 9 + tap]);
        }
    }
    if (idx < 4096) {
        if (f32) {
            ws[OFF_W1F + idx] = ((const float*)W1)[idx];
            ws[OFF_W2F + idx] = ((const float*)W2)[idx];
        } else {
            ws[OFF_W1F + idx] = bf2f_raw(((const unsigned short*)W1)[idx]);
            ws[OFF_W2F + idx] = bf2f_raw(((const unsigned short*)W2)[idx]);
        }
    }
    if (idx < 8192)
        ws[OFF_WOUTF + idx] = f32 ? ((const float*)Wout)[idx]
                                  : bf2f_raw(((const unsigned short*)Wout)[idx]);
    if (idx < 128) {
        if (f32) {
            ws[OFF_A1F + idx]   = ((const float*)a1)[idx];
            ws[OFF_A2F + idx]   = ((const float*)a2)[idx];
            ws[OFF_AOUTF + idx] = ((const float*)aout)[idx];
        } else {
            ws[OFF_A1F + idx]   = bf2f_raw(((const unsigned short*)a1)[idx]);
            ws[OFF_A2F + idx]   = bf2f_raw(((const unsigned short*)a2)[idx]);
            ws[OFF_AOUTF + idx] = bf2f_raw(((const unsigned short*)aout)[idx]);
        }
    }
    if (idx < 64) {
        if (f32) {
            ws[OFF_CBF + idx] = ((const float*)conv_b)[idx];
            ws[OFF_TBF + idx] = ((const float*)tconv_b)[idx];
        } else {
            ws[OFF_CBF + idx] = bf2f_raw(((const unsigned short*)conv_b)[idx]);
            ws[OFF_TBF + idx] = bf2f_raw(((const unsigned short*)tconv_b)[idx]);
        }
    }
}

// ---------------------------------------------------------------------------
// K1: 3x3 stride-2 conv pad 1 + fused sq atomic.  Reads x directly (dual
// dtype).  Writes featT (BUF0, channel-major) and feat_nc (BUF2, node-major).
// grid (18, 16 oc-groups, B) x 128.
// ---------------------------------------------------------------------------
template <bool F32>
__device__ __forceinline__ void conv_body(const void* __restrict__ x,
                                          float* __restrict__ ws,
                                          int n, int ocb, int b)
{
    int oy = n / 48, ox = n - (n / 48) * 48;
    const float* wc2 = ws + OFF_WC2;
    size_t xb = (size_t)b * 64 * 9216;
    float acc[4] = {0, 0, 0, 0};

    for (int ky = 0; ky < 3; ++ky) {
        int iy = 2 * oy - 1 + ky;
        bool vy = (unsigned)iy < 96u;
        int iyc = vy ? iy : 0;
        for (int kx = 0; kx < 3; ++kx) {
            int ix = 2 * ox - 1 + kx;
            bool v = vy && ((unsigned)ix < 96u);
            int ixc = v ? ix : 0;
            size_t xoff = xb + iyc * 96 + ixc;
            const float* wb = wc2 + (ky * 3 + kx) * 4096 + ocb;
            #pragma unroll 8
            for (int ic = 0; ic < 64; ++ic) {
                float xv;
                if (F32) xv = ((const float*)x)[xoff + ic * 9216];
                else     xv = bf2f_raw(((const unsigned short*)x)[xoff + ic * 9216]);
                xv = v ? xv : 0.f;
                const float* wr = wb + ic * 64;
                #pragma unroll
                for (int o = 0; o < 4; ++o) acc[o] += xv * wr[o];
            }
        }
    }
    float* featT = ws + OFF_BUF0 + (size_t)b * 64 * N_;
    const float* cb = ws + OFF_CBF;
    float ssum = 0.f;
    #pragma unroll
    for (int o = 0; o < 4; ++o) {
        float f = acc[o] + cb[ocb + o];
        acc[o] = f;
        featT[(ocb + o) * N_ + n] = f;
        ssum += f * f;
    }
    *(float4*)(ws + OFF_BUF2 + ((size_t)(b * N_ + n) * 64 + ocb)) =
        make_float4(acc[0], acc[1], acc[2], acc[3]);
    atomicAdd(ws + OFF_SQ + b * N_ + n, ssum);
}

__global__ __launch_bounds__(128) void k1_conv(const void* __restrict__ x,
                                               float* __restrict__ ws)
{
    int n   = blockIdx.x * 128 + threadIdx.x;   // 0..2303
    int ocb = blockIdx.y * 4;
    int b   = blockIdx.z;
    if (ws[OFF_FLAG] != 0.f) conv_body<true >(x, ws, n, ocb, b);
    else                     conv_body<false>(x, ws, n, ocb, b);
}

// ---------------------------------------------------------------------------
// K2: exact top-7 per row over a third of j.  Block = 4 waves = 16 rows;
// j-range 768 = 6 tiles of 128.  A(16x64) in LDS (staged once), B(64x128)
// staged coalesced per tile from channel-major featT.  Wave owns 4 rows;
// lane owns 2 j (lane, lane+64).  Per 4k: 4 A-b128 (broadcast) + 8 B-b32
// (2-way free) + 32 FMA.  Keys u64 (mono(y)<<32|j), strict < == stable
// argsort.  Per-lane static-index insert (spill-free, proven R6/R7), final
// 7-pass butterfly merge -> sorted partial to PK.  grid (288, 3) x 256.
// ---------------------------------------------------------------------------
__global__ __launch_bounds__(256) void k2_knn(float* __restrict__ ws)
{
    __shared__ float As[16][64];
    __shared__ float Bs[64][128];
    int tid = threadIdx.x;
    int i0  = blockIdx.x * 16;            // global row base (16 | N_)
    int jh  = blockIdx.y;                 // 0..2
    int b   = i0 / N_;
    const float* fT = ws + OFF_BUF0 + (size_t)b * 64 * N_;
    const float* sq = ws + OFF_SQ + b * N_;
    int w = tid >> 6, lane = tid & 63;
    int r0 = w * 4;

    {   // stage A rows (node-major, coalesced float4)
        int r = tid >> 4, c4 = tid & 15;
        float4 v = ((const float4*)(ws + OFF_BUF2))[(size_t)(i0 + r) * 16 + c4];
        *(float4*)&As[r][c4 * 4] = v;
    }

    u64 K[4][7];
    #pragma unroll
    for (int r = 0; r < 4; ++r)
        #pragma unroll
        for (int t = 0; t < 7; ++t) K[r][t] = ~0ull;

    __syncthreads();

    for (int jt = 0; jt < 6; ++jt) {
        int jb = jh * 768 + jt * 128;
        // stage B tile [64k][128j]: 2048 float4 / 256 thr = 8 iters, coalesced
        #pragma unroll
        for (int it = 0; it < 8; ++it) {
            int idx = tid + it * 256;       // < 2048
            int k = idx >> 5, j4 = idx & 31;
            float4 v = *(const float4*)(fT + (size_t)k * N_ + jb + j4 * 4);
            *(float4*)&Bs[k][j4 * 4] = v;
        }
        __syncthreads();

        float accA[4] = {0, 0, 0, 0};   // j = jb + lane
        float accB[4] = {0, 0, 0, 0};   // j = jb + lane + 64
        #pragma unroll 4
        for (int k4 = 0; k4 < 16; ++k4) {
            float4 av[4];
            #pragma unroll
            for (int r = 0; r < 4; ++r)
                av[r] = *(const float4*)&As[r0 + r][k4 * 4];
            float b0 = Bs[k4 * 4 + 0][lane],      b1 = Bs[k4 * 4 + 1][lane];
            float b2 = Bs[k4 * 4 + 2][lane],      b3 = Bs[k4 * 4 + 3][lane];
            float c0 = Bs[k4 * 4 + 0][lane + 64], c1 = Bs[k4 * 4 + 1][lane + 64];
            float c2 = Bs[k4 * 4 + 2][lane + 64], c3 = Bs[k4 * 4 + 3][lane + 64];
            #pragma unroll
            for (int r = 0; r < 4; ++r) {
                accA[r] += av[r].x * b0 + av[r].y * b1 + av[r].z * b2 + av[r].w * b3;
                accB[r] += av[r].x * c0 + av[r].y * c1 + av[r].z * c2 + av[r].w * c3;
            }
        }

        int jA = jb + lane, jB = jb + lane + 64;
        float sqA = sq[jA], sqB = sq[jB];
        #pragma unroll
        for (int r = 0; r < 4; ++r) {
            #pragma unroll
            for (int q = 0; q < 2; ++q) {
                int j = q ? jB : jA;
                float y = (q ? sqB : sqA) - 2.f * (q ? accB[r] : accA[r]);
                u64 key = ((u64)mono32(y) << 32) | (unsigned int)j;
                if (key < K[r][6]) {
                    int pos = 0;
                    #pragma unroll
                    for (int s = 0; s < 7; ++s) pos += (K[r][s] < key) ? 1 : 0;
                    #pragma unroll
                    for (int p = 6; p > 0; --p)
                        K[r][p] = (p == pos) ? key : ((p > pos) ? K[r][p - 1] : K[r][p]);
                    if (pos == 0) K[r][0] = key;
                }
            }
        }
        __syncthreads();
    }

    // 7-pass wave merge per row (scan-min + butterfly + blank; R7-proven)
    u64* pk = (u64*)(ws + OFF_PK);
    #pragma unroll
    for (int r = 0; r < 4; ++r) {
        u64 myk = 0;
        for (int pass = 0; pass < 7; ++pass) {
            u64 m = K[r][0];
            #pragma unroll
            for (int s = 1; s < 7; ++s) m = (K[r][s] < m) ? K[r][s] : m;
            #pragma unroll
            for (int off = 1; off < 64; off <<= 1) {
                u64 o = (u64)__shfl_xor((long long)m, off);
                m = (o < m) ? o : m;
            }
            #pragma unroll
            for (int s = 0; s < 7; ++s)
                if (K[r][s] == m) K[r][s] = ~0ull;
            if (lane == pass) myk = m;
        }
        if (lane < 7)
            pk[((size_t)(i0 + r0 + r) * 3 + jh) * 8 + lane] = myk;
    }
}

// ---------------------------------------------------------------------------
// K2M: 3-way rank-merge of sorted 7-lists per row -> KNN.  grid 18 x 256.
// ---------------------------------------------------------------------------
__global__ __launch_bounds__(256) void k2_merge(float* __restrict__ ws)
{
    int row = blockIdx.x * 256 + threadIdx.x;   // < 4608
    const u64* pk = (const u64*)(ws + OFF_PK) + (size_t)row * 24;
    int* kout = (int*)(ws + OFF_KNN) + (size_t)row * 8;
    u64 L0[7], L1[7], L2[7];
    #pragma unroll
    for (int q = 0; q < 7; ++q) { L0[q] = pk[q]; L1[q] = pk[8 + q]; L2[q] = pk[16 + q]; }
    #pragma unroll
    for (int q = 0; q < 7; ++q) {
        int rank = q;
        #pragma unroll
        for (int p = 0; p < 7; ++p) rank += ((L1[p] < L0[q]) ? 1 : 0) + ((L2[p] < L0[q]) ? 1 : 0);
        if (rank < 7) kout[rank] = (int)(L0[q] & 0xffffffffull);
    }
    #pragma unroll
    for (int q = 0; q < 7; ++q) {
        int rank = q;
        #pragma unroll
        for (int p = 0; p < 7; ++p) rank += ((L0[p] < L1[q]) ? 1 : 0) + ((L2[p] < L1[q]) ? 1 : 0);
        if (rank < 7) kout[rank] = (int)(L1[q] & 0xffffffffull);
    }
    #pragma unroll
    for (int q = 0; q < 7; ++q) {
        int rank = q;
        #pragma unroll
        for (int p = 0; p < 7; ++p) rank += ((L0[p] < L2[q]) ? 1 : 0) + ((L1[p] < L2[q]) ? 1 : 0);
        if (rank < 7) kout[rank] = (int)(L2[q] & 0xffffffffull);
    }
}

// ---------------------------------------------------------------------------
// K_lin: both GAT input projections; node-major Wh_nc out + s1/s2 atomics.
// grid (18, 32) x 256: y = layer*16 + ocg (4 oc each).
// ---------------------------------------------------------------------------
__global__ __launch_bounds__(256) void k_lin(float* __restrict__ ws)
{
    int g = blockIdx.y;
    int layer = g >> 4;
    int ocb = (g & 15) * 4;
    const float* W  = ws + (layer ? OFF_W2F : OFF_W1F);
    const float* a  = ws + (layer ? OFF_A2F : OFF_A1F);
    float* out_nc   = ws + (layer ? OFF_BUF3 : OFF_BUF1);
    float* s1       = ws + (layer ? OFF_S21 : OFF_S11);
    float* s2       = ws + (layer ? OFF_S22 : OFF_S12);
    int i = blockIdx.x * 256 + threadIdx.x;
    int b = i / N_, n = i - b * N_;
    const float* in_b = ws + OFF_BUF0 + (size_t)b * 64 * N_;

    float acc[4] = {0, 0, 0, 0};
    #pragma unroll 8
    for (int kk = 0; kk < 64; ++kk) {
        float xv = in_b[kk * N_ + n];
        const float* wr = W + kk * 64 + ocb;
        #pragma unroll
        for (int o = 0; o < 4; ++o) acc[o] += xv * wr[o];
    }
    *(float4*)(out_nc + ((size_t)i * 64 + ocb)) =
        make_float4(acc[0], acc[1], acc[2], acc[3]);
    float p1 = 0.f, p2 = 0.f;
    #pragma unroll
    for (int o = 0; o < 4; ++o) {
        p1 += acc[o] * a[ocb + o];
        p2 += acc[o] * a[64 + ocb + o];
    }
    atomicAdd(s1 + i, p1);
    atomicAdd(s2 + i, p2);
}

// ---------------------------------------------------------------------------
// K_lin2: Whout_nc = [h1|h2] @ Wout.  h1=BUF2, h2=BUF0 (channel-major),
// out=BUF1 node-major.  grid (18, 16) x 256, 4 oc each.
// ---------------------------------------------------------------------------
__global__ __launch_bounds__(256) void k_lin2(float* __restrict__ ws)
{
    int ocb = blockIdx.y * 4;
    int i = blockIdx.x * 256 + threadIdx.x;
    int b = i / N_, n = i - b * N_;
    const float* h1 = ws + OFF_BUF2 + (size_t)b * 64 * N_;
    const float* h2 = ws + OFF_BUF0 + (size_t)b * 64 * N_;
    const float* W  = ws + OFF_WOUTF;
    const float* a  = ws + OFF_AOUTF;

    float acc[4] = {0, 0, 0, 0};
    #pragma unroll 8
    for (int kk = 0; kk < 64; ++kk) {
        float xv = h1[kk * N_ + n];
        const float* wr = W + kk * 64 + ocb;
        #pragma unroll
        for (int o = 0; o < 4; ++o) acc[o] += xv * wr[o];
    }
    #pragma unroll 8
    for (int kk = 0; kk < 64; ++kk) {
        float xv = h2[kk * N_ + n];
        const float* wr = W + (64 + kk) * 64 + ocb;
        #pragma unroll
        for (int o = 0; o < 4; ++o) acc[o] += xv * wr[o];
    }
    *(float4*)(ws + OFF_BUF1 + ((size_t)i * 64 + ocb)) =
        make_float4(acc[0], acc[1], acc[2], acc[3]);
    float p1 = 0.f, p2 = 0.f;
    #pragma unroll
    for (int o = 0; o < 4; ++o) {
        p1 += acc[o] * a[ocb + o];
        p2 += acc[o] * a[64 + ocb + o];
    }
    atomicAdd(ws + OFF_S1O + i, p1);
    atomicAdd(ws + OFF_S2O + i, p2);
}

// ---------------------------------------------------------------------------
// attention body: softmax over 7-NN + ELU, one float4 channel group.
// ---------------------------------------------------------------------------
__device__ __forceinline__ void attn_body(
    const float* __restrict__ Wh_nc, const float* __restrict__ s1,
    const float* __restrict__ s2, const int* __restrict__ knn,
    float* __restrict__ out, int i, int b, int n, int c4)
{
    const int* kp = knn + (size_t)i * 8;
    int j[7];
    #pragma unroll
    for (int t = 0; t < 7; ++t) {
        int jt = kp[t];
        j[t] = ((unsigned)jt < (unsigned)N_) ? jt : 0;
    }
    float si = s1[i];
    const float* s2b = s2 + b * N_;
    float e[7];
    #pragma unroll
    for (int t = 0; t < 7; ++t) {
        float v = si + s2b[j[t]];
        e[t] = v > 0.f ? v : 0.2f * v;     // leaky_relu 0.2
    }
    float m = e[0];
    #pragma unroll
    for (int t = 1; t < 7; ++t) m = fmaxf(m, e[t]);
    float ssum = 0.f;
    #pragma unroll
    for (int t = 0; t < 7; ++t) { e[t] = __expf(e[t] - m); ssum += e[t]; }
    float inv = 1.f / ssum;
    #pragma unroll
    for (int t = 0; t < 7; ++t) e[t] *= inv;

    const float4* W4 = (const float4*)Wh_nc;
    float4 acc = make_float4(0.f, 0.f, 0.f, 0.f);
    #pragma unroll
    for (int t = 0; t < 7; ++t) {
        float4 v = W4[(size_t)(b * N_ + j[t]) * 16 + c4];
        acc.x += e[t] * v.x; acc.y += e[t] * v.y;
        acc.z += e[t] * v.z; acc.w += e[t] * v.w;
    }
    acc.x = acc.x > 0.f ? acc.x : expm1f(acc.x);
    acc.y = acc.y > 0.f ? acc.y : expm1f(acc.y);
    acc.z = acc.z > 0.f ? acc.z : expm1f(acc.z);
    acc.w = acc.w > 0.f ? acc.w : expm1f(acc.w);
    float* ob = out + (size_t)b * 64 * N_;
    ob[(c4 * 4 + 0) * N_ + n] = acc.x;
    ob[(c4 * 4 + 1) * N_ + n] = acc.y;
    ob[(c4 * 4 + 2) * N_ + n] = acc.z;
    ob[(c4 * 4 + 3) * N_ + n] = acc.w;
}

// grid (18, 16 c4-groups, 2 layers) x 256
__global__ __launch_bounds__(256) void k_attn12(float* __restrict__ ws)
{
    int layer = blockIdx.z;
    const float* Wh_nc = ws + (layer ? OFF_BUF3 : OFF_BUF1);
    const float* s1    = ws + (layer ? OFF_S21 : OFF_S11);
    const float* s2    = ws + (layer ? OFF_S22 : OFF_S12);
    float* out         = ws + (layer ? OFF_BUF0 : OFF_BUF2);
    int c4 = blockIdx.y;
    int i = blockIdx.x * 256 + threadIdx.x;
    int b = i / N_, n = i - b * N_;
    attn_body(Wh_nc, s1, s2, (const int*)(ws + OFF_KNN), out, i, b, n, c4);
}

// grid (18, 16) x 256
__global__ __launch_bounds__(256) void k_attn_out(float* __restrict__ ws)
{
    int c4 = blockIdx.y;
    int i = blockIdx.x * 256 + threadIdx.x;
    int b = i / N_, n = i - b * N_;
    attn_body(ws + OFF_BUF1, ws + OFF_S1O, ws + OFF_S2O,
              (const int*)(ws + OFF_KNN), ws + OFF_BUF3, i, b, n, c4);
}

// ---------------------------------------------------------------------------
// K7: ConvTranspose2d k=3 s=2 p=1 op=1 : 48x48 -> 96x96, reads g=BUF3.
// grid (36, 16 oc, B) x 256, 4 oc each; dual-dtype output store.
// ---------------------------------------------------------------------------
__global__ __launch_bounds__(256) void k7_tconv(float* __restrict__ ws,
                                                void* __restrict__ outp)
{
    bool f32 = ws[OFF_FLAG] != 0.f;
    int pix = blockIdx.x * 256 + threadIdx.x;   // 0..9215
    int ocb = blockIdx.y * 4;
    int b   = blockIdx.z;
    int oy = pix / 96, ox = pix - (pix / 96) * 96;

    const float* gT  = ws + OFF_BUF3 + (size_t)b * 64 * N_;
    const float* wt2 = ws + OFF_WT2;
    float acc[4] = {0, 0, 0, 0};

    for (int ky = 0; ky < 3; ++ky) {
        int ty = oy + 1 - ky;
        bool vy = ((ty & 1) == 0) && ((unsigned)(ty >> 1) < 48u);
        int iy = vy ? (ty >> 1) : 0;
        for (int kx = 0; kx < 3; ++kx) {
            int tx = ox + 1 - kx;
            bool v = vy && ((tx & 1) == 0) && ((unsigned)(tx >> 1) < 48u);
            int ix = v ? (tx >> 1) : 0;
            const float* gp = gT + iy * 48 + ix;
            const float* wb = wt2 + (ky * 3 + kx) * 4096 + ocb;
            #pragma unroll 8
            for (int ic = 0; ic < 64; ++ic) {
                float gv = gp[ic * N_];
                gv = v ? gv : 0.f;
                const float* wr = wb + ic * 64;
                #pragma unroll
                for (int o = 0; o < 4; ++o) acc[o] += gv * wr[o];
            }
        }
    }
    const float* tb = ws + OFF_TBF;
    size_t base = ((size_t)(b * 64 + ocb) * 96 + oy) * 96 + ox;
    if (f32) {
        float* op = (float*)outp;
        #pragma unroll
        for (int o = 0; o < 4; ++o) op[base + (size_t)o * 9216] = acc[o] + tb[ocb + o];
    } else {
        bf16* op = (bf16*)outp;
        #pragma unroll
        for (int o = 0; o < 4; ++o)
            op[base + (size_t)o * 9216] = __float2bfloat16(acc[o] + tb[ocb + o]);
    }
}

// ---------------------------------------------------------------------------
extern "C" void kernel_launch(void* const* d_in, const int* in_sizes, int n_in,
                              void* d_out, int out_size, void* d_ws, size_t ws_size,
                              hipStream_t stream)
{
    float* ws = (float*)d_ws;

    hipLaunchKernelGGL(kc_prep, dim3(144), dim3(256), 0, stream,
                       d_in[1], d_in[2], d_in[3], d_in[4], d_in[5], d_in[6],
                       d_in[7], d_in[8], d_in[9], d_in[10], ws);
    hipLaunchKernelGGL(k1_conv, dim3(18, 16, 2), dim3(128), 0, stream, d_in[0], ws);
    hipLaunchKernelGGL(k2_knn, dim3(288, 3), dim3(256), 0, stream, ws);
    hipLaunchKernelGGL(k2_merge, dim3(18), dim3(256), 0, stream, ws);
    hipLaunchKernelGGL(k_lin, dim3(18, 32), dim3(256), 0, stream, ws);
    hipLaunchKernelGGL(k_attn12, dim3(18, 16, 2), dim3(256), 0, stream, ws);
    hipLaunchKernelGGL(k_lin2, dim3(18, 16), dim3(256), 0, stream, ws);
    hipLaunchKernelGGL(k_attn_out, dim3(18, 16), dim3(256), 0, stream, ws);
    hipLaunchKernelGGL(k7_tconv, dim3(36, 16, 2), dim3(256), 0, stream, ws, d_out);
}

// Round 10
// 247.522 us; speedup vs baseline: 1.7695x; 1.2186x over previous
//
#include <hip/hip_runtime.h>
#include <hip/hip_bf16.h>
#include <stdint.h>

using bf16 = __hip_bfloat16;
using u64 = unsigned long long;

constexpr int B_ = 2;
constexpr int N_ = 2304;   // 48*48 post-conv nodes

// Workspace layout (float offsets). Max = 1,560,640 floats = 6.24 MB
// (<= 6.54 MB proven in R3).
constexpr int OFF_WC2   = 0;        // conv w  [tap][ic][oc] (9*64*64)
constexpr int OFF_WT2   = 36864;    // tconv w [tap][ic][oc]
constexpr int OFF_W1F   = 73728;    // [64][64]
constexpr int OFF_W2F   = 77824;
constexpr int OFF_WOUTF = 81920;    // [128][64]
constexpr int OFF_A1F   = 90112;    // 128
constexpr int OFF_A2F   = 90240;
constexpr int OFF_AOUTF = 90368;
constexpr int OFF_CBF   = 90496;    // 64
constexpr int OFF_TBF   = 90560;    // 64
constexpr int OFF_FLAG  = 90624;    // 1: fp32 inputs; 0: bf16
constexpr int OFF_SQ    = 90688;    // [B*N]; SQ + six s-arrays contiguous (zeroed by kc)
constexpr int OFF_S11   = 95296;
constexpr int OFF_S12   = 99904;
constexpr int OFF_S21   = 104512;
constexpr int OFF_S22   = 109120;
constexpr int OFF_S1O   = 113728;
constexpr int OFF_S2O   = 118336;
constexpr int OFF_KNN   = 122944;   // int [B*N][8] (7 used)
constexpr int OFF_BUF0  = 159808;   // 294912 floats each
constexpr int OFF_BUF1  = 454720;
constexpr int OFF_BUF2  = 749632;
constexpr int OFF_BUF3  = 1044544;
constexpr int OFF_PK    = 1339456;  // DEDICATED u64[4608][3][8] partials (884 KB)
// Lifetimes:
//  BUF0: featT   (k1 -> k2 B-tiles, k_lin) -> h2       (attn12 -> lin2)
//  BUF1: Wh1_nc  (k_lin -> attn12)         -> Whout_nc (lin2 -> attn_out)
//  BUF2: feat_nc (k1 -> k2 A-rows)         -> h1       (attn12 -> lin2)
//  BUF3: Wh2_nc  (k_lin -> attn12)         -> g        (attn_out -> k7)
//  PK:   k2 -> merge slice of k_lin (dedicated, no aliasing)

__device__ __forceinline__ float bf2f_raw(unsigned short u) {
    return __uint_as_float(((unsigned int)u) << 16);
}

// order-preserving float -> u32 map
__device__ __forceinline__ unsigned int mono32(float f) {
    unsigned int u = __float_as_uint(f);
    return (u & 0x80000000u) ? ~u : (u | 0x80000000u);
}

// Dtype probe: 64 low-halves of conv_w; fp32 misread -> huge bf16 values.
__device__ __forceinline__ bool detect_f32(const void* conv_w) {
    const unsigned short* cw = (const unsigned short*)conv_w;
    float m = 0.f;
    #pragma unroll
    for (int u = 0; u < 64; ++u) {
        float v = fabsf(bf2f_raw(cw[u]));
        if (v < 3.0e38f) m = fmaxf(m, v);
    }
    return m > 1.0e4f;
}

// ---------------------------------------------------------------------------
// KC: weight convert/transpose + zero s-arrays + write dtype flag.
// grid 144 x 256.
// ---------------------------------------------------------------------------
__global__ __launch_bounds__(256) void kc_prep(
    const void* conv_w, const void* conv_b, const void* W1, const void* a1,
    const void* W2, const void* a2, const void* Wout, const void* aout,
    const void* tconv_w, const void* tconv_b, float* __restrict__ ws)
{
    bool f32 = detect_f32(conv_w);
    int idx = blockIdx.x * 256 + threadIdx.x;   // < 36864
    if (idx == 0) ws[OFF_FLAG] = f32 ? 1.f : 0.f;
    if (idx < 32256) ws[OFF_SQ + idx] = 0.f;    // SQ..S2O zero-init

    {
        int tap = idx >> 12, ic = (idx >> 6) & 63, oc = idx & 63;
        if (f32) {
            ws[OFF_WC2 + idx] = ((const float*)conv_w)[(oc * 64 + ic) * 9 + tap];
            ws[OFF_WT2 + idx] = ((const float*)tconv_w)[(ic * 64 + oc) * 9 + tap];
        } else {
            ws[OFF_WC2 + idx] = bf2f_raw(((const unsigned short*)conv_w)[(oc * 64 + ic) * 9 + tap]);
            ws[OFF_WT2 + idx] = bf2f_raw(((const unsigned short*)tconv_w)[(ic * 64 + oc) * 9 + tap]);
        }
    }
    if (idx < 4096) {
        if (f32) {
            ws[OFF_W1F + idx] = ((const float*)W1)[idx];
            ws[OFF_W2F + idx] = ((const float*)W2)[idx];
        } else {
            ws[OFF_W1F + idx] = bf2f_raw(((const unsigned short*)W1)[idx]);
            ws[OFF_W2F + idx] = bf2f_raw(((const unsigned short*)W2)[idx]);
        }
    }
    if (idx < 8192)
        ws[OFF_WOUTF + idx] = f32 ? ((const float*)Wout)[idx]
                                  : bf2f_raw(((const unsigned short*)Wout)[idx]);
    if (idx < 128) {
        if (f32) {
            ws[OFF_A1F + idx]   = ((const float*)a1)[idx];
            ws[OFF_A2F + idx]   = ((const float*)a2)[idx];
            ws[OFF_AOUTF + idx] = ((const float*)aout)[idx];
        } else {
            ws[OFF_A1F + idx]   = bf2f_raw(((const unsigned short*)a1)[idx]);
            ws[OFF_A2F + idx]   = bf2f_raw(((const unsigned short*)a2)[idx]);
            ws[OFF_AOUTF + idx] = bf2f_raw(((const unsigned short*)aout)[idx]);
        }
    }
    if (idx < 64) {
        if (f32) {
            ws[OFF_CBF + idx] = ((const float*)conv_b)[idx];
            ws[OFF_TBF + idx] = ((const float*)tconv_b)[idx];
        } else {
            ws[OFF_CBF + idx] = bf2f_raw(((const unsigned short*)conv_b)[idx]);
            ws[OFF_TBF + idx] = bf2f_raw(((const unsigned short*)tconv_b)[idx]);
        }
    }
}

// ---------------------------------------------------------------------------
// K1: 3x3 stride-2 conv pad 1 + fused sq atomic.  Reads x directly (dual
// dtype).  Writes featT (BUF0, channel-major) and feat_nc (BUF2, node-major).
// grid (18, 16 oc-groups, B) x 128.
// ---------------------------------------------------------------------------
template <bool F32>
__device__ __forceinline__ void conv_body(const void* __restrict__ x,
                                          float* __restrict__ ws,
                                          int n, int ocb, int b)
{
    int oy = n / 48, ox = n - (n / 48) * 48;
    const float* wc2 = ws + OFF_WC2;
    size_t xb = (size_t)b * 64 * 9216;
    float acc[4] = {0, 0, 0, 0};

    for (int ky = 0; ky < 3; ++ky) {
        int iy = 2 * oy - 1 + ky;
        bool vy = (unsigned)iy < 96u;
        int iyc = vy ? iy : 0;
        for (int kx = 0; kx < 3; ++kx) {
            int ix = 2 * ox - 1 + kx;
            bool v = vy && ((unsigned)ix < 96u);
            int ixc = v ? ix : 0;
            size_t xoff = xb + iyc * 96 + ixc;
            const float* wb = wc2 + (ky * 3 + kx) * 4096 + ocb;
            #pragma unroll 8
            for (int ic = 0; ic < 64; ++ic) {
                float xv;
                if (F32) xv = ((const float*)x)[xoff + ic * 9216];
                else     xv = bf2f_raw(((const unsigned short*)x)[xoff + ic * 9216]);
                xv = v ? xv : 0.f;
                const float* wr = wb + ic * 64;
                #pragma unroll
                for (int o = 0; o < 4; ++o) acc[o] += xv * wr[o];
            }
        }
    }
    float* featT = ws + OFF_BUF0 + (size_t)b * 64 * N_;
    const float* cb = ws + OFF_CBF;
    float ssum = 0.f;
    #pragma unroll
    for (int o = 0; o < 4; ++o) {
        float f = acc[o] + cb[ocb + o];
        acc[o] = f;
        featT[(ocb + o) * N_ + n] = f;
        ssum += f * f;
    }
    *(float4*)(ws + OFF_BUF2 + ((size_t)(b * N_ + n) * 64 + ocb)) =
        make_float4(acc[0], acc[1], acc[2], acc[3]);
    atomicAdd(ws + OFF_SQ + b * N_ + n, ssum);
}

__global__ __launch_bounds__(128) void k1_conv(const void* __restrict__ x,
                                               float* __restrict__ ws)
{
    int n   = blockIdx.x * 128 + threadIdx.x;   // 0..2303
    int ocb = blockIdx.y * 4;
    int b   = blockIdx.z;
    if (ws[OFF_FLAG] != 0.f) conv_body<true >(x, ws, n, ocb, b);
    else                     conv_body<false>(x, ws, n, ocb, b);
}

// ---------------------------------------------------------------------------
// K2: exact top-7 per row over a third of j.  Block = 4 waves = 16 rows;
// j-range 768 = 6 tiles of 128.  A(16x64) in LDS, B(64x128) staged coalesced
// from channel-major featT.  Wave owns 4 rows; LANE OWNS ADJACENT j-PAIR
// (2*lane, 2*lane+1) so B reads are b64: per 4k = 4 A-b128 + 4 B-b64 + 32 FMA.
// Keys u64 (mono(y)<<32|j), strict < == stable argsort.  Per-lane static
// insert (spill-free), 7-pass butterfly merge -> sorted partial to PK.
// grid (288, 3) x 256.
// ---------------------------------------------------------------------------
__global__ __launch_bounds__(256) void k2_knn(float* __restrict__ ws)
{
    __shared__ float As[16][64];
    __shared__ float Bs[64][128];
    int tid = threadIdx.x;
    int i0  = blockIdx.x * 16;            // global row base (16 | N_)
    int jh  = blockIdx.y;                 // 0..2
    int b   = i0 / N_;
    const float* fT = ws + OFF_BUF0 + (size_t)b * 64 * N_;
    const float* sq = ws + OFF_SQ + b * N_;
    int w = tid >> 6, lane = tid & 63;
    int r0 = w * 4;

    {   // stage A rows (node-major, coalesced float4)
        int r = tid >> 4, c4 = tid & 15;
        float4 v = ((const float4*)(ws + OFF_BUF2))[(size_t)(i0 + r) * 16 + c4];
        *(float4*)&As[r][c4 * 4] = v;
    }

    u64 K[4][7];
    #pragma unroll
    for (int r = 0; r < 4; ++r)
        #pragma unroll
        for (int t = 0; t < 7; ++t) K[r][t] = ~0ull;

    __syncthreads();

    for (int jt = 0; jt < 6; ++jt) {
        int jb = jh * 768 + jt * 128;
        // stage B tile [64k][128j]: 2048 float4 / 256 thr = 8 iters, coalesced
        #pragma unroll
        for (int it = 0; it < 8; ++it) {
            int idx = tid + it * 256;       // < 2048
            int k = idx >> 5, j4 = idx & 31;
            float4 v = *(const float4*)(fT + (size_t)k * N_ + jb + j4 * 4);
            *(float4*)&Bs[k][j4 * 4] = v;
        }
        __syncthreads();

        int jA = jb + 2 * lane, jB = jA + 1;
        float accA[4] = {0, 0, 0, 0};
        float accB[4] = {0, 0, 0, 0};
        #pragma unroll 4
        for (int k4 = 0; k4 < 16; ++k4) {
            float4 av[4];
            #pragma unroll
            for (int r = 0; r < 4; ++r)
                av[r] = *(const float4*)&As[r0 + r][k4 * 4];
            float2 p0 = *(const float2*)&Bs[k4 * 4 + 0][2 * lane];
            float2 p1 = *(const float2*)&Bs[k4 * 4 + 1][2 * lane];
            float2 p2 = *(const float2*)&Bs[k4 * 4 + 2][2 * lane];
            float2 p3 = *(const float2*)&Bs[k4 * 4 + 3][2 * lane];
            #pragma unroll
            for (int r = 0; r < 4; ++r) {
                accA[r] += av[r].x * p0.x + av[r].y * p1.x + av[r].z * p2.x + av[r].w * p3.x;
                accB[r] += av[r].x * p0.y + av[r].y * p1.y + av[r].z * p2.y + av[r].w * p3.y;
            }
        }

        float sqA = sq[jA], sqB = sq[jB];
        #pragma unroll
        for (int r = 0; r < 4; ++r) {
            #pragma unroll
            for (int q = 0; q < 2; ++q) {
                int j = q ? jB : jA;
                float y = (q ? sqB : sqA) - 2.f * (q ? accB[r] : accA[r]);
                u64 key = ((u64)mono32(y) << 32) | (unsigned int)j;
                if (key < K[r][6]) {
                    int pos = 0;
                    #pragma unroll
                    for (int s = 0; s < 7; ++s) pos += (K[r][s] < key) ? 1 : 0;
                    #pragma unroll
                    for (int p = 6; p > 0; --p)
                        K[r][p] = (p == pos) ? key : ((p > pos) ? K[r][p - 1] : K[r][p]);
                    if (pos == 0) K[r][0] = key;
                }
            }
        }
        __syncthreads();
    }

    // 7-pass wave merge per row (scan-min + butterfly + blank)
    u64* pk = (u64*)(ws + OFF_PK);
    #pragma unroll
    for (int r = 0; r < 4; ++r) {
        u64 myk = 0;
        for (int pass = 0; pass < 7; ++pass) {
            u64 m = K[r][0];
            #pragma unroll
            for (int s = 1; s < 7; ++s) m = (K[r][s] < m) ? K[r][s] : m;
            #pragma unroll
            for (int off = 1; off < 64; off <<= 1) {
                u64 o = (u64)__shfl_xor((long long)m, off);
                m = (o < m) ? o : m;
            }
            #pragma unroll
            for (int s = 0; s < 7; ++s)
                if (K[r][s] == m) K[r][s] = ~0ull;
            if (lane == pass) myk = m;
        }
        if (lane < 7)
            pk[((size_t)(i0 + r0 + r) * 3 + jh) * 8 + lane] = myk;
    }
}

// ---------------------------------------------------------------------------
// K_lin: both GAT input projections + (fused) 3-way KNN rank-merge slice.
// grid (18, 33) x 256: y<32 -> layer*16+ocg projection; y==32 -> merge.
// ---------------------------------------------------------------------------
__global__ __launch_bounds__(256) void k_lin(float* __restrict__ ws)
{
    int g = blockIdx.y;
    if (g == 32) {   // 3-way rank-merge of sorted 7-lists per row -> KNN
        int row = blockIdx.x * 256 + threadIdx.x;   // < 4608
        const u64* pk = (const u64*)(ws + OFF_PK) + (size_t)row * 24;
        int* kout = (int*)(ws + OFF_KNN) + (size_t)row * 8;
        u64 L0[7], L1[7], L2[7];
        #pragma unroll
        for (int q = 0; q < 7; ++q) { L0[q] = pk[q]; L1[q] = pk[8 + q]; L2[q] = pk[16 + q]; }
        #pragma unroll
        for (int q = 0; q < 7; ++q) {
            int rank = q;
            #pragma unroll
            for (int p = 0; p < 7; ++p)
                rank += ((L1[p] < L0[q]) ? 1 : 0) + ((L2[p] < L0[q]) ? 1 : 0);
            if (rank < 7) kout[rank] = (int)(L0[q] & 0xffffffffull);
        }
        #pragma unroll
        for (int q = 0; q < 7; ++q) {
            int rank = q;
            #pragma unroll
            for (int p = 0; p < 7; ++p)
                rank += ((L0[p] < L1[q]) ? 1 : 0) + ((L2[p] < L1[q]) ? 1 : 0);
            if (rank < 7) kout[rank] = (int)(L1[q] & 0xffffffffull);
        }
        #pragma unroll
        for (int q = 0; q < 7; ++q) {
            int rank = q;
            #pragma unroll
            for (int p = 0; p < 7; ++p)
                rank += ((L0[p] < L2[q]) ? 1 : 0) + ((L1[p] < L2[q]) ? 1 : 0);
            if (rank < 7) kout[rank] = (int)(L2[q] & 0xffffffffull);
        }
        return;
    }
    int layer = g >> 4;
    int ocb = (g & 15) * 4;
    const float* W  = ws + (layer ? OFF_W2F : OFF_W1F);
    const float* a  = ws + (layer ? OFF_A2F : OFF_A1F);
    float* out_nc   = ws + (layer ? OFF_BUF3 : OFF_BUF1);
    float* s1       = ws + (layer ? OFF_S21 : OFF_S11);
    float* s2       = ws + (layer ? OFF_S22 : OFF_S12);
    int i = blockIdx.x * 256 + threadIdx.x;
    int b = i / N_, n = i - b * N_;
    const float* in_b = ws + OFF_BUF0 + (size_t)b * 64 * N_;

    float acc[4] = {0, 0, 0, 0};
    #pragma unroll 8
    for (int kk = 0; kk < 64; ++kk) {
        float xv = in_b[kk * N_ + n];
        const float* wr = W + kk * 64 + ocb;
        #pragma unroll
        for (int o = 0; o < 4; ++o) acc[o] += xv * wr[o];
    }
    *(float4*)(out_nc + ((size_t)i * 64 + ocb)) =
        make_float4(acc[0], acc[1], acc[2], acc[3]);
    float p1 = 0.f, p2 = 0.f;
    #pragma unroll
    for (int o = 0; o < 4; ++o) {
        p1 += acc[o] * a[ocb + o];
        p2 += acc[o] * a[64 + ocb + o];
    }
    atomicAdd(s1 + i, p1);
    atomicAdd(s2 + i, p2);
}

// ---------------------------------------------------------------------------
// K_lin2: Whout_nc = [h1|h2] @ Wout.  h1=BUF2, h2=BUF0 (channel-major),
// out=BUF1 node-major.  grid (18, 16) x 256, 4 oc each.
// ---------------------------------------------------------------------------
__global__ __launch_bounds__(256) void k_lin2(float* __restrict__ ws)
{
    int ocb = blockIdx.y * 4;
    int i = blockIdx.x * 256 + threadIdx.x;
    int b = i / N_, n = i - b * N_;
    const float* h1 = ws + OFF_BUF2 + (size_t)b * 64 * N_;
    const float* h2 = ws + OFF_BUF0 + (size_t)b * 64 * N_;
    const float* W  = ws + OFF_WOUTF;
    const float* a  = ws + OFF_AOUTF;

    float acc[4] = {0, 0, 0, 0};
    #pragma unroll 8
    for (int kk = 0; kk < 64; ++kk) {
        float xv = h1[kk * N_ + n];
        const float* wr = W + kk * 64 + ocb;
        #pragma unroll
        for (int o = 0; o < 4; ++o) acc[o] += xv * wr[o];
    }
    #pragma unroll 8
    for (int kk = 0; kk < 64; ++kk) {
        float xv = h2[kk * N_ + n];
        const float* wr = W + (64 + kk) * 64 + ocb;
        #pragma unroll
        for (int o = 0; o < 4; ++o) acc[o] += xv * wr[o];
    }
    *(float4*)(ws + OFF_BUF1 + ((size_t)i * 64 + ocb)) =
        make_float4(acc[0], acc[1], acc[2], acc[3]);
    float p1 = 0.f, p2 = 0.f;
    #pragma unroll
    for (int o = 0; o < 4; ++o) {
        p1 += acc[o] * a[ocb + o];
        p2 += acc[o] * a[64 + ocb + o];
    }
    atomicAdd(ws + OFF_S1O + i, p1);
    atomicAdd(ws + OFF_S2O + i, p2);
}

// ---------------------------------------------------------------------------
// attention body: softmax over 7-NN + ELU, one float4 channel group.
// ---------------------------------------------------------------------------
__device__ __forceinline__ void attn_body(
    const float* __restrict__ Wh_nc, const float* __restrict__ s1,
    const float* __restrict__ s2, const int* __restrict__ knn,
    float* __restrict__ out, int i, int b, int n, int c4)
{
    const int* kp = knn + (size_t)i * 8;
    int j[7];
    #pragma unroll
    for (int t = 0; t < 7; ++t) {
        int jt = kp[t];
        j[t] = ((unsigned)jt < (unsigned)N_) ? jt : 0;
    }
    float si = s1[i];
    const float* s2b = s2 + b * N_;
    float e[7];
    #pragma unroll
    for (int t = 0; t < 7; ++t) {
        float v = si + s2b[j[t]];
        e[t] = v > 0.f ? v : 0.2f * v;     // leaky_relu 0.2
    }
    float m = e[0];
    #pragma unroll
    for (int t = 1; t < 7; ++t) m = fmaxf(m, e[t]);
    float ssum = 0.f;
    #pragma unroll
    for (int t = 0; t < 7; ++t) { e[t] = __expf(e[t] - m); ssum += e[t]; }
    float inv = 1.f / ssum;
    #pragma unroll
    for (int t = 0; t < 7; ++t) e[t] *= inv;

    const float4* W4 = (const float4*)Wh_nc;
    float4 acc = make_float4(0.f, 0.f, 0.f, 0.f);
    #pragma unroll
    for (int t = 0; t < 7; ++t) {
        float4 v = W4[(size_t)(b * N_ + j[t]) * 16 + c4];
        acc.x += e[t] * v.x; acc.y += e[t] * v.y;
        acc.z += e[t] * v.z; acc.w += e[t] * v.w;
    }
    acc.x = acc.x > 0.f ? acc.x : expm1f(acc.x);
    acc.y = acc.y > 0.f ? acc.y : expm1f(acc.y);
    acc.z = acc.z > 0.f ? acc.z : expm1f(acc.z);
    acc.w = acc.w > 0.f ? acc.w : expm1f(acc.w);
    float* ob = out + (size_t)b * 64 * N_;
    ob[(c4 * 4 + 0) * N_ + n] = acc.x;
    ob[(c4 * 4 + 1) * N_ + n] = acc.y;
    ob[(c4 * 4 + 2) * N_ + n] = acc.z;
    ob[(c4 * 4 + 3) * N_ + n] = acc.w;
}

// grid (18, 16 c4-groups, 2 layers) x 256
__global__ __launch_bounds__(256) void k_attn12(float* __restrict__ ws)
{
    int layer = blockIdx.z;
    const float* Wh_nc = ws + (layer ? OFF_BUF3 : OFF_BUF1);
    const float* s1    = ws + (layer ? OFF_S21 : OFF_S11);
    const float* s2    = ws + (layer ? OFF_S22 : OFF_S12);
    float* out         = ws + (layer ? OFF_BUF0 : OFF_BUF2);
    int c4 = blockIdx.y;
    int i = blockIdx.x * 256 + threadIdx.x;
    int b = i / N_, n = i - b * N_;
    attn_body(Wh_nc, s1, s2, (const int*)(ws + OFF_KNN), out, i, b, n, c4);
}

// grid (18, 16) x 256
__global__ __launch_bounds__(256) void k_attn_out(float* __restrict__ ws)
{
    int c4 = blockIdx.y;
    int i = blockIdx.x * 256 + threadIdx.x;
    int b = i / N_, n = i - b * N_;
    attn_body(ws + OFF_BUF1, ws + OFF_S1O, ws + OFF_S2O,
              (const int*)(ws + OFF_KNN), ws + OFF_BUF3, i, b, n, c4);
}

// ---------------------------------------------------------------------------
// K7: ConvTranspose2d k=3 s=2 p=1 op=1 : 48x48 -> 96x96, reads g=BUF3.
// PARITY-SPECIALIZED: block owns one (oy,ox) parity class -> wave-uniform
// valid-tap set (1/2/2/4 taps), zero wasted FMA.  8 oc per thread.
// grid (18, 32 = pc*8+ocg, B) x 128; dual-dtype output store.
// ---------------------------------------------------------------------------
__global__ __launch_bounds__(128) void k7_tconv(float* __restrict__ ws,
                                                void* __restrict__ outp)
{
    bool f32 = ws[OFF_FLAG] != 0.f;
    int pixc = blockIdx.x * 128 + threadIdx.x;   // 0..2303 within class
    int g    = blockIdx.y;
    int pc   = g >> 3, ocb = (g & 7) * 8;
    int b    = blockIdx.z;
    int py = pc >> 1, px = pc & 1;
    int ay = pixc / 48, bx = pixc - (pixc / 48) * 48;
    int oy = 2 * ay + py, ox = 2 * bx + px;

    const float* gT  = ws + OFF_BUF3 + (size_t)b * 64 * N_;
    const float* wt2 = ws + OFF_WT2;
    float acc[8] = {0, 0, 0, 0, 0, 0, 0, 0};

    int nky = py ? 2 : 1;
    int nkx = px ? 2 : 1;
    for (int s = 0; s < nky; ++s) {
        int ky = py ? (s == 0 ? 0 : 2) : 1;
        int iy = py ? (s == 0 ? ay + 1 : ay) : ay;
        bool vy = iy < 48;
        for (int t = 0; t < nkx; ++t) {
            int kx = px ? (t == 0 ? 0 : 2) : 1;
            int ix = px ? (t == 0 ? bx + 1 : bx) : bx;
            bool v = vy && (ix < 48);
            const float* gp = gT + (v ? iy * 48 + ix : 0);
            const float* wb = wt2 + (ky * 3 + kx) * 4096 + ocb;
            #pragma unroll 8
            for (int ic = 0; ic < 64; ++ic) {
                float gv = gp[ic * N_];
                gv = v ? gv : 0.f;
                const float* wr = wb + ic * 64;
                #pragma unroll
                for (int o = 0; o < 8; ++o) acc[o] += gv * wr[o];
            }
        }
    }
    const float* tb = ws + OFF_TBF;
    size_t base = ((size_t)(b * 64 + ocb) * 96 + oy) * 96 + ox;
    if (f32) {
        float* op = (float*)outp;
        #pragma unroll
        for (int o = 0; o < 8; ++o) op[base + (size_t)o * 9216] = acc[o] + tb[ocb + o];
    } else {
        bf16* op = (bf16*)outp;
        #pragma unroll
        for (int o = 0; o < 8; ++o)
            op[base + (size_t)o * 9216] = __float2bfloat16(acc[o] + tb[ocb + o]);
    }
}

// ---------------------------------------------------------------------------
extern "C" void kernel_launch(void* const* d_in, const int* in_sizes, int n_in,
                              void* d_out, int out_size, void* d_ws, size_t ws_size,
                              hipStream_t stream)
{
    float* ws = (float*)d_ws;

    hipLaunchKernelGGL(kc_prep, dim3(144), dim3(256), 0, stream,
                       d_in[1], d_in[2], d_in[3], d_in[4], d_in[5], d_in[6],
                       d_in[7], d_in[8], d_in[9], d_in[10], ws);
    hipLaunchKernelGGL(k1_conv, dim3(18, 16, 2), dim3(128), 0, stream, d_in[0], ws);
    hipLaunchKernelGGL(k2_knn, dim3(288, 3), dim3(256), 0, stream, ws);
    hipLaunchKernelGGL(k_lin, dim3(18, 33), dim3(256), 0, stream, ws);
    hipLaunchKernelGGL(k_attn12, dim3(18, 16, 2), dim3(256), 0, stream, ws);
    hipLaunchKernelGGL(k_lin2, dim3(18, 16), dim3(256), 0, stream, ws);
    hipLaunchKernelGGL(k_attn_out, dim3(18, 16), dim3(256), 0, stream, ws);
    hipLaunchKernelGGL(k7_tconv, dim3(18, 32, 2), dim3(128), 0, stream, ws, d_out);
}

// Round 11
// 238.077 us; speedup vs baseline: 1.8397x; 1.0397x over previous
//
#include <hip/hip_runtime.h>
#include <hip/hip_bf16.h>
#include <stdint.h>

using bf16 = __hip_bfloat16;
using u64 = unsigned long long;

constexpr int B_ = 2;
constexpr int N_ = 2304;   // 48*48 post-conv nodes

// Workspace layout (float offsets). Max = 1,560,640 floats = 6.24 MB (== R10).
constexpr int OFF_WC2   = 0;        // conv w  [tap][ic][oc] (9*64*64)
constexpr int OFF_WT2   = 36864;    // tconv w [tap][ic][oc]
constexpr int OFF_W1F   = 73728;    // [64][64]
constexpr int OFF_W2F   = 77824;
constexpr int OFF_WOUTF = 81920;    // [128][64]
constexpr int OFF_A1F   = 90112;    // 128
constexpr int OFF_A2F   = 90240;
constexpr int OFF_AOUTF = 90368;
constexpr int OFF_CBF   = 90496;    // 64
constexpr int OFF_TBF   = 90560;    // 64
constexpr int OFF_FLAG  = 90624;    // 1: fp32 inputs; 0: bf16
constexpr int OFF_SQ    = 90688;    // [B*N]; SQ + six s-arrays contiguous (zeroed by kc)
constexpr int OFF_S11   = 95296;
constexpr int OFF_S12   = 99904;
constexpr int OFF_S21   = 104512;
constexpr int OFF_S22   = 109120;
constexpr int OFF_S1O   = 113728;
constexpr int OFF_S2O   = 118336;
constexpr int OFF_KNN   = 122944;   // int [B*N][8] (7 used)
constexpr int OFF_BUF0  = 159808;   // 294912 floats each
constexpr int OFF_BUF1  = 454720;
constexpr int OFF_BUF2  = 749632;
constexpr int OFF_BUF3  = 1044544;
constexpr int OFF_PK    = 1339456;  // DEDICATED u64[4608][3][8] partials (884 KB)
// Lifetimes:
//  BUF0: featT   (k1 -> k2 B-tiles, k_lin) -> h2       (attn12 -> lin2)
//  BUF1: Wh1_nc  (k_lin -> attn12)         -> Whout_nc (lin2 -> attn_out)
//  BUF2: feat_nc (k1 -> k2 A-rows)         -> h1       (attn12 -> lin2)
//  BUF3: Wh2_nc  (k_lin -> attn12)         -> g        (attn_out -> k7)
//  PK:   k2 -> merge slice of k_lin (dedicated, no aliasing)

__device__ __forceinline__ float bf2f_raw(unsigned short u) {
    return __uint_as_float(((unsigned int)u) << 16);
}

// order-preserving float -> u32 map
__device__ __forceinline__ unsigned int mono32(float f) {
    unsigned int u = __float_as_uint(f);
    return (u & 0x80000000u) ? ~u : (u | 0x80000000u);
}

// Dtype probe: 64 low-halves of conv_w; fp32 misread -> huge bf16 values.
__device__ __forceinline__ bool detect_f32(const void* conv_w) {
    const unsigned short* cw = (const unsigned short*)conv_w;
    float m = 0.f;
    #pragma unroll
    for (int u = 0; u < 64; ++u) {
        float v = fabsf(bf2f_raw(cw[u]));
        if (v < 3.0e38f) m = fmaxf(m, v);
    }
    return m > 1.0e4f;
}

// ---------------------------------------------------------------------------
// KC: weight convert/transpose + zero s-arrays + write dtype flag.
// grid 144 x 256.
// ---------------------------------------------------------------------------
__global__ __launch_bounds__(256) void kc_prep(
    const void* conv_w, const void* conv_b, const void* W1, const void* a1,
    const void* W2, const void* a2, const void* Wout, const void* aout,
    const void* tconv_w, const void* tconv_b, float* __restrict__ ws)
{
    bool f32 = detect_f32(conv_w);
    int idx = blockIdx.x * 256 + threadIdx.x;   // < 36864
    if (idx == 0) ws[OFF_FLAG] = f32 ? 1.f : 0.f;
    if (idx < 32256) ws[OFF_SQ + idx] = 0.f;    // SQ..S2O zero-init

    {
        int tap = idx >> 12, ic = (idx >> 6) & 63, oc = idx & 63;
        if (f32) {
            ws[OFF_WC2 + idx] = ((const float*)conv_w)[(oc * 64 + ic) * 9 + tap];
            ws[OFF_WT2 + idx] = ((const float*)tconv_w)[(ic * 64 + oc) * 9 + tap];
        } else {
            ws[OFF_WC2 + idx] = bf2f_raw(((const unsigned short*)conv_w)[(oc * 64 + ic) * 9 + tap]);
            ws[OFF_WT2 + idx] = bf2f_raw(((const unsigned short*)tconv_w)[(ic * 64 + oc) * 9 + tap]);
        }
    }
    if (idx < 4096) {
        if (f32) {
            ws[OFF_W1F + idx] = ((const float*)W1)[idx];
            ws[OFF_W2F + idx] = ((const float*)W2)[idx];
        } else {
            ws[OFF_W1F + idx] = bf2f_raw(((const unsigned short*)W1)[idx]);
            ws[OFF_W2F + idx] = bf2f_raw(((const unsigned short*)W2)[idx]);
        }
    }
    if (idx < 8192)
        ws[OFF_WOUTF + idx] = f32 ? ((const float*)Wout)[idx]
                                  : bf2f_raw(((const unsigned short*)Wout)[idx]);
    if (idx < 128) {
        if (f32) {
            ws[OFF_A1F + idx]   = ((const float*)a1)[idx];
            ws[OFF_A2F + idx]   = ((const float*)a2)[idx];
            ws[OFF_AOUTF + idx] = ((const float*)aout)[idx];
        } else {
            ws[OFF_A1F + idx]   = bf2f_raw(((const unsigned short*)a1)[idx]);
            ws[OFF_A2F + idx]   = bf2f_raw(((const unsigned short*)a2)[idx]);
            ws[OFF_AOUTF + idx] = bf2f_raw(((const unsigned short*)aout)[idx]);
        }
    }
    if (idx < 64) {
        if (f32) {
            ws[OFF_CBF + idx] = ((const float*)conv_b)[idx];
            ws[OFF_TBF + idx] = ((const float*)tconv_b)[idx];
        } else {
            ws[OFF_CBF + idx] = bf2f_raw(((const unsigned short*)conv_b)[idx]);
            ws[OFF_TBF + idx] = bf2f_raw(((const unsigned short*)tconv_b)[idx]);
        }
    }
}

// ---------------------------------------------------------------------------
// K1: 3x3 stride-2 conv pad 1 + fused sq atomic.  Reads x directly (dual
// dtype).  Writes featT (BUF0, channel-major) and feat_nc (BUF2, node-major).
// grid (18, 16 oc-groups, B) x 128.
// ---------------------------------------------------------------------------
template <bool F32>
__device__ __forceinline__ void conv_body(const void* __restrict__ x,
                                          float* __restrict__ ws,
                                          int n, int ocb, int b)
{
    int oy = n / 48, ox = n - (n / 48) * 48;
    const float* wc2 = ws + OFF_WC2;
    size_t xb = (size_t)b * 64 * 9216;
    float acc[4] = {0, 0, 0, 0};

    for (int ky = 0; ky < 3; ++ky) {
        int iy = 2 * oy - 1 + ky;
        bool vy = (unsigned)iy < 96u;
        int iyc = vy ? iy : 0;
        for (int kx = 0; kx < 3; ++kx) {
            int ix = 2 * ox - 1 + kx;
            bool v = vy && ((unsigned)ix < 96u);
            int ixc = v ? ix : 0;
            size_t xoff = xb + iyc * 96 + ixc;
            const float* wb = wc2 + (ky * 3 + kx) * 4096 + ocb;
            #pragma unroll 8
            for (int ic = 0; ic < 64; ++ic) {
                float xv;
                if (F32) xv = ((const float*)x)[xoff + ic * 9216];
                else     xv = bf2f_raw(((const unsigned short*)x)[xoff + ic * 9216]);
                xv = v ? xv : 0.f;
                const float* wr = wb + ic * 64;
                #pragma unroll
                for (int o = 0; o < 4; ++o) acc[o] += xv * wr[o];
            }
        }
    }
    float* featT = ws + OFF_BUF0 + (size_t)b * 64 * N_;
    const float* cb = ws + OFF_CBF;
    float ssum = 0.f;
    #pragma unroll
    for (int o = 0; o < 4; ++o) {
        float f = acc[o] + cb[ocb + o];
        acc[o] = f;
        featT[(ocb + o) * N_ + n] = f;
        ssum += f * f;
    }
    *(float4*)(ws + OFF_BUF2 + ((size_t)(b * N_ + n) * 64 + ocb)) =
        make_float4(acc[0], acc[1], acc[2], acc[3]);
    atomicAdd(ws + OFF_SQ + b * N_ + n, ssum);
}

__global__ __launch_bounds__(128) void k1_conv(const void* __restrict__ x,
                                               float* __restrict__ ws)
{
    int n   = blockIdx.x * 128 + threadIdx.x;   // 0..2303
    int ocb = blockIdx.y * 4;
    int b   = blockIdx.z;
    if (ws[OFF_FLAG] != 0.f) conv_body<true >(x, ws, n, ocb, b);
    else                     conv_body<false>(x, ws, n, ocb, b);
}

// ---------------------------------------------------------------------------
// K2: exact top-7 per row, FMA-bound rebuild.
// Block = 4 waves = 32 rows (wave owns 8); j-range 768 = 3 tiles of 256.
// A: wave-uniform global float4 reads of feat_nc (readfirstlane-forced ->
//    s_load_dwordx4 on the scalar pipe; zero LDS/VALU-pipe cost).
// B: k-halved tile Bs[32][256] staged coalesced; lane owns j = 4*lane..+3 ->
//    b128 reads; per k4-chunk: 4 B-b128 + 8 s_loads + 128 FMA  (FMA-bound).
// y -> ys LDS; selection: 8 threads/row, interleaved j (bank-spread), each a
// 7-key u64 list (static idx, spill-free), then 8-lane shfl_xor consume-min
// merge -> sorted partial to PK.  Keys u64 (mono(y)<<32|j) == stable argsort.
// grid (144, 3) x 256.  LDS = 32 KB (Bs) + 33.3 KB (ys) -> 2 blocks/CU.
// ---------------------------------------------------------------------------
__global__ __launch_bounds__(256) void k2_knn(float* __restrict__ ws)
{
    __shared__ float Bs[32][256];
    __shared__ float ys[32][260];     // pad 4: selection banks spread
    int tid = threadIdx.x;
    int i0  = blockIdx.x * 32;        // global row base (32 | N_, no straddle)
    int jh  = blockIdx.y;             // 0..2
    int b   = i0 / N_;
    const float* fT  = ws + OFF_BUF0 + (size_t)b * 64 * N_;
    const float* fnc = ws + OFF_BUF2;                 // node-major [row][64]
    const float* sq  = ws + OFF_SQ + b * N_;
    int w = tid >> 6, lane = tid & 63;
    int r0 = w * 8;
    int arow0 = __builtin_amdgcn_readfirstlane(i0 + r0);  // uniform A row base

    u64 K[7];
    #pragma unroll
    for (int t = 0; t < 7; ++t) K[t] = ~0ull;

    int rsel = r0 + (lane >> 3);      // selection: 8 threads per row
    int g    = lane & 7;

    for (int jt = 0; jt < 3; ++jt) {
        int jb = jh * 768 + jt * 256;
        float acc[8][4];
        #pragma unroll
        for (int r = 0; r < 8; ++r)
            #pragma unroll
            for (int c = 0; c < 4; ++c) acc[r][c] = 0.f;

        for (int kh = 0; kh < 2; ++kh) {
            __syncthreads();          // Bs safe to overwrite
            #pragma unroll
            for (int it = 0; it < 8; ++it) {
                int idx = tid + it * 256;     // < 2048
                int k = idx >> 6, j4 = idx & 63;
                float4 v = *(const float4*)(fT + (size_t)(kh * 32 + k) * N_ + jb + j4 * 4);
                *(float4*)&Bs[k][j4 * 4] = v;
            }
            __syncthreads();

            #pragma unroll 2
            for (int k4 = 0; k4 < 8; ++k4) {
                float4 Bv[4];
                #pragma unroll
                for (int kk = 0; kk < 4; ++kk)
                    Bv[kk] = *(const float4*)&Bs[k4 * 4 + kk][4 * lane];
                #pragma unroll
                for (int r = 0; r < 8; ++r) {
                    // wave-uniform -> s_load_dwordx4 (scalar pipe)
                    float4 a = *(const float4*)(fnc + (size_t)(arow0 + r) * 64
                                                + kh * 32 + k4 * 4);
                    acc[r][0] += a.x * Bv[0].x + a.y * Bv[1].x + a.z * Bv[2].x + a.w * Bv[3].x;
                    acc[r][1] += a.x * Bv[0].y + a.y * Bv[1].y + a.z * Bv[2].y + a.w * Bv[3].y;
                    acc[r][2] += a.x * Bv[0].z + a.y * Bv[1].z + a.z * Bv[2].z + a.w * Bv[3].z;
                    acc[r][3] += a.x * Bv[0].w + a.y * Bv[1].w + a.z * Bv[2].w + a.w * Bv[3].w;
                }
            }
        }

        // y = sq[j] - 2*dot  -> ys (b128 writes, same-wave rows)
        float4 sqv = *(const float4*)(sq + jb + 4 * lane);
        #pragma unroll
        for (int r = 0; r < 8; ++r) {
            float4 yv;
            yv.x = sqv.x - 2.f * acc[r][0];
            yv.y = sqv.y - 2.f * acc[r][1];
            yv.z = sqv.z - 2.f * acc[r][2];
            yv.w = sqv.w - 2.f * acc[r][3];
            *(float4*)&ys[r0 + r][4 * lane] = yv;
        }

        // selection: thread scans interleaved j = g + 8u (bank-spread b32)
        #pragma unroll 8
        for (int u = 0; u < 32; ++u) {
            int jl = g + 8 * u;
            float y = ys[rsel][jl];
            u64 key = ((u64)mono32(y) << 32) | (unsigned int)(jb + jl);
            if (key < K[6]) {
                int pos = 0;
                #pragma unroll
                for (int s = 0; s < 7; ++s) pos += (K[s] < key) ? 1 : 0;
                #pragma unroll
                for (int p = 6; p > 0; --p)
                    K[p] = (p == pos) ? key : ((p > pos) ? K[p - 1] : K[p]);
                if (pos == 0) K[0] = key;
            }
        }
        __syncthreads();   // ys consumed before next tile's GEMM overwrites
    }

    // merge 8 per-thread lists per row (8-lane groups, xor 1/2/4), sorted out
    u64 myk = 0;
    for (int pass = 0; pass < 7; ++pass) {
        u64 m = K[0];
        #pragma unroll
        for (int s = 1; s < 7; ++s) m = (K[s] < m) ? K[s] : m;
        #pragma unroll
        for (int off = 1; off < 8; off <<= 1) {
            u64 o = (u64)__shfl_xor((long long)m, off);
            m = (o < m) ? o : m;
        }
        #pragma unroll
        for (int s = 0; s < 7; ++s)
            if (K[s] == m) K[s] = ~0ull;
        if (g == pass) myk = m;
    }
    if (g < 7) {
        u64* pk = (u64*)(ws + OFF_PK);
        pk[((size_t)(i0 + rsel) * 3 + jh) * 8 + g] = myk;
    }
}

// ---------------------------------------------------------------------------
// K_lin: both GAT input projections + (fused) 3-way KNN rank-merge slice.
// grid (18, 33) x 256: y<32 -> layer*16+ocg projection; y==32 -> merge.
// ---------------------------------------------------------------------------
__global__ __launch_bounds__(256) void k_lin(float* __restrict__ ws)
{
    int g = blockIdx.y;
    if (g == 32) {   // 3-way rank-merge of sorted 7-lists per row -> KNN
        int row = blockIdx.x * 256 + threadIdx.x;   // < 4608
        const u64* pk = (const u64*)(ws + OFF_PK) + (size_t)row * 24;
        int* kout = (int*)(ws + OFF_KNN) + (size_t)row * 8;
        u64 L0[7], L1[7], L2[7];
        #pragma unroll
        for (int q = 0; q < 7; ++q) { L0[q] = pk[q]; L1[q] = pk[8 + q]; L2[q] = pk[16 + q]; }
        #pragma unroll
        for (int q = 0; q < 7; ++q) {
            int rank = q;
            #pragma unroll
            for (int p = 0; p < 7; ++p)
                rank += ((L1[p] < L0[q]) ? 1 : 0) + ((L2[p] < L0[q]) ? 1 : 0);
            if (rank < 7) kout[rank] = (int)(L0[q] & 0xffffffffull);
        }
        #pragma unroll
        for (int q = 0; q < 7; ++q) {
            int rank = q;
            #pragma unroll
            for (int p = 0; p < 7; ++p)
                rank += ((L0[p] < L1[q]) ? 1 : 0) + ((L2[p] < L1[q]) ? 1 : 0);
            if (rank < 7) kout[rank] = (int)(L1[q] & 0xffffffffull);
        }
        #pragma unroll
        for (int q = 0; q < 7; ++q) {
            int rank = q;
            #pragma unroll
            for (int p = 0; p < 7; ++p)
                rank += ((L0[p] < L2[q]) ? 1 : 0) + ((L1[p] < L2[q]) ? 1 : 0);
            if (rank < 7) kout[rank] = (int)(L2[q] & 0xffffffffull);
        }
        return;
    }
    int layer = g >> 4;
    int ocb = (g & 15) * 4;
    const float* W  = ws + (layer ? OFF_W2F : OFF_W1F);
    const float* a  = ws + (layer ? OFF_A2F : OFF_A1F);
    float* out_nc   = ws + (layer ? OFF_BUF3 : OFF_BUF1);
    float* s1       = ws + (layer ? OFF_S21 : OFF_S11);
    float* s2       = ws + (layer ? OFF_S22 : OFF_S12);
    int i = blockIdx.x * 256 + threadIdx.x;
    int b = i / N_, n = i - b * N_;
    const float* in_b = ws + OFF_BUF0 + (size_t)b * 64 * N_;

    float acc[4] = {0, 0, 0, 0};
    #pragma unroll 8
    for (int kk = 0; kk < 64; ++kk) {
        float xv = in_b[kk * N_ + n];
        const float* wr = W + kk * 64 + ocb;
        #pragma unroll
        for (int o = 0; o < 4; ++o) acc[o] += xv * wr[o];
    }
    *(float4*)(out_nc + ((size_t)i * 64 + ocb)) =
        make_float4(acc[0], acc[1], acc[2], acc[3]);
    float p1 = 0.f, p2 = 0.f;
    #pragma unroll
    for (int o = 0; o < 4; ++o) {
        p1 += acc[o] * a[ocb + o];
        p2 += acc[o] * a[64 + ocb + o];
    }
    atomicAdd(s1 + i, p1);
    atomicAdd(s2 + i, p2);
}

// ---------------------------------------------------------------------------
// K_lin2: Whout_nc = [h1|h2] @ Wout.  h1=BUF2, h2=BUF0 (channel-major),
// out=BUF1 node-major.  grid (18, 16) x 256, 4 oc each.
// ---------------------------------------------------------------------------
__global__ __launch_bounds__(256) void k_lin2(float* __restrict__ ws)
{
    int ocb = blockIdx.y * 4;
    int i = blockIdx.x * 256 + threadIdx.x;
    int b = i / N_, n = i - b * N_;
    const float* h1 = ws + OFF_BUF2 + (size_t)b * 64 * N_;
    const float* h2 = ws + OFF_BUF0 + (size_t)b * 64 * N_;
    const float* W  = ws + OFF_WOUTF;
    const float* a  = ws + OFF_AOUTF;

    float acc[4] = {0, 0, 0, 0};
    #pragma unroll 8
    for (int kk = 0; kk < 64; ++kk) {
        float xv = h1[kk * N_ + n];
        const float* wr = W + kk * 64 + ocb;
        #pragma unroll
        for (int o = 0; o < 4; ++o) acc[o] += xv * wr[o];
    }
    #pragma unroll 8
    for (int kk = 0; kk < 64; ++kk) {
        float xv = h2[kk * N_ + n];
        const float* wr = W + (64 + kk) * 64 + ocb;
        #pragma unroll
        for (int o = 0; o < 4; ++o) acc[o] += xv * wr[o];
    }
    *(float4*)(ws + OFF_BUF1 + ((size_t)i * 64 + ocb)) =
        make_float4(acc[0], acc[1], acc[2], acc[3]);
    float p1 = 0.f, p2 = 0.f;
    #pragma unroll
    for (int o = 0; o < 4; ++o) {
        p1 += acc[o] * a[ocb + o];
        p2 += acc[o] * a[64 + ocb + o];
    }
    atomicAdd(ws + OFF_S1O + i, p1);
    atomicAdd(ws + OFF_S2O + i, p2);
}

// ---------------------------------------------------------------------------
// attention body: softmax over 7-NN + ELU, one float4 channel group.
// ---------------------------------------------------------------------------
__device__ __forceinline__ void attn_body(
    const float* __restrict__ Wh_nc, const float* __restrict__ s1,
    const float* __restrict__ s2, const int* __restrict__ knn,
    float* __restrict__ out, int i, int b, int n, int c4)
{
    const int* kp = knn + (size_t)i * 8;
    int j[7];
    #pragma unroll
    for (int t = 0; t < 7; ++t) {
        int jt = kp[t];
        j[t] = ((unsigned)jt < (unsigned)N_) ? jt : 0;
    }
    float si = s1[i];
    const float* s2b = s2 + b * N_;
    float e[7];
    #pragma unroll
    for (int t = 0; t < 7; ++t) {
        float v = si + s2b[j[t]];
        e[t] = v > 0.f ? v : 0.2f * v;     // leaky_relu 0.2
    }
    float m = e[0];
    #pragma unroll
    for (int t = 1; t < 7; ++t) m = fmaxf(m, e[t]);
    float ssum = 0.f;
    #pragma unroll
    for (int t = 0; t < 7; ++t) { e[t] = __expf(e[t] - m); ssum += e[t]; }
    float inv = 1.f / ssum;
    #pragma unroll
    for (int t = 0; t < 7; ++t) e[t] *= inv;

    const float4* W4 = (const float4*)Wh_nc;
    float4 acc = make_float4(0.f, 0.f, 0.f, 0.f);
    #pragma unroll
    for (int t = 0; t < 7; ++t) {
        float4 v = W4[(size_t)(b * N_ + j[t]) * 16 + c4];
        acc.x += e[t] * v.x; acc.y += e[t] * v.y;
        acc.z += e[t] * v.z; acc.w += e[t] * v.w;
    }
    acc.x = acc.x > 0.f ? acc.x : expm1f(acc.x);
    acc.y = acc.y > 0.f ? acc.y : expm1f(acc.y);
    acc.z = acc.z > 0.f ? acc.z : expm1f(acc.z);
    acc.w = acc.w > 0.f ? acc.w : expm1f(acc.w);
    float* ob = out + (size_t)b * 64 * N_;
    ob[(c4 * 4 + 0) * N_ + n] = acc.x;
    ob[(c4 * 4 + 1) * N_ + n] = acc.y;
    ob[(c4 * 4 + 2) * N_ + n] = acc.z;
    ob[(c4 * 4 + 3) * N_ + n] = acc.w;
}

// grid (18, 16 c4-groups, 2 layers) x 256
__global__ __launch_bounds__(256) void k_attn12(float* __restrict__ ws)
{
    int layer = blockIdx.z;
    const float* Wh_nc = ws + (layer ? OFF_BUF3 : OFF_BUF1);
    const float* s1    = ws + (layer ? OFF_S21 : OFF_S11);
    const float* s2    = ws + (layer ? OFF_S22 : OFF_S12);
    float* out         = ws + (layer ? OFF_BUF0 : OFF_BUF2);
    int c4 = blockIdx.y;
    int i = blockIdx.x * 256 + threadIdx.x;
    int b = i / N_, n = i - b * N_;
    attn_body(Wh_nc, s1, s2, (const int*)(ws + OFF_KNN), out, i, b, n, c4);
}

// grid (18, 16) x 256
__global__ __launch_bounds__(256) void k_attn_out(float* __restrict__ ws)
{
    int c4 = blockIdx.y;
    int i = blockIdx.x * 256 + threadIdx.x;
    int b = i / N_, n = i - b * N_;
    attn_body(ws + OFF_BUF1, ws + OFF_S1O, ws + OFF_S2O,
              (const int*)(ws + OFF_KNN), ws + OFF_BUF3, i, b, n, c4);
}

// ---------------------------------------------------------------------------
// K7: ConvTranspose2d k=3 s=2 p=1 op=1 : 48x48 -> 96x96, reads g=BUF3.
// PARITY-SPECIALIZED: block owns one (oy,ox) parity class -> wave-uniform
// valid-tap set (1/2/2/4 taps), zero wasted FMA.  8 oc per thread.
// grid (18, 32 = pc*8+ocg, B) x 128; dual-dtype output store.
// ---------------------------------------------------------------------------
__global__ __launch_bounds__(128) void k7_tconv(float* __restrict__ ws,
                                                void* __restrict__ outp)
{
    bool f32 = ws[OFF_FLAG] != 0.f;
    int pixc = blockIdx.x * 128 + threadIdx.x;   // 0..2303 within class
    int g    = blockIdx.y;
    int pc   = g >> 3, ocb = (g & 7) * 8;
    int b    = blockIdx.z;
    int py = pc >> 1, px = pc & 1;
    int ay = pixc / 48, bx = pixc - (pixc / 48) * 48;
    int oy = 2 * ay + py, ox = 2 * bx + px;

    const float* gT  = ws + OFF_BUF3 + (size_t)b * 64 * N_;
    const float* wt2 = ws + OFF_WT2;
    float acc[8] = {0, 0, 0, 0, 0, 0, 0, 0};

    int nky = py ? 2 : 1;
    int nkx = px ? 2 : 1;
    for (int s = 0; s < nky; ++s) {
        int ky = py ? (s == 0 ? 0 : 2) : 1;
        int iy = py ? (s == 0 ? ay + 1 : ay) : ay;
        bool vy = iy < 48;
        for (int t = 0; t < nkx; ++t) {
            int kx = px ? (t == 0 ? 0 : 2) : 1;
            int ix = px ? (t == 0 ? bx + 1 : bx) : bx;
            bool v = vy && (ix < 48);
            const float* gp = gT + (v ? iy * 48 + ix : 0);
            const float* wb = wt2 + (ky * 3 + kx) * 4096 + ocb;
            #pragma unroll 8
            for (int ic = 0; ic < 64; ++ic) {
                float gv = gp[ic * N_];
                gv = v ? gv : 0.f;
                const float* wr = wb + ic * 64;
                #pragma unroll
                for (int o = 0; o < 8; ++o) acc[o] += gv * wr[o];
            }
        }
    }
    const float* tb = ws + OFF_TBF;
    size_t base = ((size_t)(b * 64 + ocb) * 96 + oy) * 96 + ox;
    if (f32) {
        float* op = (float*)outp;
        #pragma unroll
        for (int o = 0; o < 8; ++o) op[base + (size_t)o * 9216] = acc[o] + tb[ocb + o];
    } else {
        bf16* op = (bf16*)outp;
        #pragma unroll
        for (int o = 0; o < 8; ++o)
            op[base + (size_t)o * 9216] = __float2bfloat16(acc[o] + tb[ocb + o]);
    }
}

// ---------------------------------------------------------------------------
extern "C" void kernel_launch(void* const* d_in, const int* in_sizes, int n_in,
                              void* d_out, int out_size, void* d_ws, size_t ws_size,
                              hipStream_t stream)
{
    float* ws = (float*)d_ws;

    hipLaunchKernelGGL(kc_prep, dim3(144), dim3(256), 0, stream,
                       d_in[1], d_in[2], d_in[3], d_in[4], d_in[5], d_in[6],
                       d_in[7], d_in[8], d_in[9], d_in[10], ws);
    hipLaunchKernelGGL(k1_conv, dim3(18, 16, 2), dim3(128), 0, stream, d_in[0], ws);
    hipLaunchKernelGGL(k2_knn, dim3(144, 3), dim3(256), 0, stream, ws);
    hipLaunchKernelGGL(k_lin, dim3(18, 33), dim3(256), 0, stream, ws);
    hipLaunchKernelGGL(k_attn12, dim3(18, 16, 2), dim3(256), 0, stream, ws);
    hipLaunchKernelGGL(k_lin2, dim3(18, 16), dim3(256), 0, stream, ws);
    hipLaunchKernelGGL(k_attn_out, dim3(18, 16), dim3(256), 0, stream, ws);
    hipLaunchKernelGGL(k7_tconv, dim3(18, 32, 2), dim3(128), 0, stream, ws, d_out);
}